// Round 4
// baseline (667.254 us; speedup 1.0000x reference)
//
#include <hip/hip_runtime.h>
#include <stdint.h>

typedef __attribute__((ext_vector_type(8))) short short8;
typedef __attribute__((ext_vector_type(4))) float f32x4;
typedef __attribute__((ext_vector_type(4))) unsigned short us4;

#define MFMA16(a,b,c) __builtin_amdgcn_mfma_f32_16x16x32_bf16((a),(b),(c),0,0,0)

static __device__ __forceinline__ float bf2f(unsigned short u){
  union { float f; unsigned int i; } c; c.i = ((unsigned int)u) << 16; return c.f;
}
static __device__ __forceinline__ unsigned short f2bf(float f){
  union { float f; unsigned int i; } c; c.f = f;
  unsigned int x = c.i;
  unsigned int r = x + 0x7fffu + ((x >> 16) & 1u);
  return (unsigned short)(r >> 16);
}

typedef const __attribute__((address_space(1))) void cg_void;
typedef __attribute__((address_space(3))) void lds_void;
static __device__ __forceinline__ void gl_lds16(const void* g, void* l){
  __builtin_amdgcn_global_load_lds((cg_void*)g, (lds_void*)l, 16, 0, 0);
}

#define MROWS 10240LL   // padded M rows for 256-tile GEMM

// ---- convert g: f32 [10000][10000] -> bf16 [10240][10048], pad rows+cols zero ----
__global__ void k_conv_g(const float* __restrict__ g, unsigned short* __restrict__ o){
  const int CH = 2512; // 10048/4 chunks per row
  const long long total = 10240LL * CH;
  for (long long i = (long long)blockIdx.x*blockDim.x + threadIdx.x; i < total;
       i += (long long)gridDim.x*blockDim.x){
    int r = (int)(i / CH);
    int c4 = (int)(i % CH) * 4;
    us4 v = {0,0,0,0};
    if (r < 10000 && c4 < 10000){
      float4 f = *(const float4*)(g + (long long)r*10000 + c4);
      v.x = f2bf(f.x); v.y = f2bf(f.y); v.z = f2bf(f.z); v.w = f2bf(f.w);
    }
    *(us4*)(o + (long long)r*10048 + c4) = v;
  }
}

// ---- convert the 3 weight matrices in one launch ----
__global__ void k_conv_w(const float* __restrict__ a, unsigned short* __restrict__ oa, int na4,
                         const float* __restrict__ b, unsigned short* __restrict__ ob, int nb4,
                         const float* __restrict__ c, unsigned short* __restrict__ oc, int nc4){
  for (int i = blockIdx.x*blockDim.x + threadIdx.x; i < na4 + nb4 + nc4;
       i += gridDim.x*blockDim.x){
    const float* src; unsigned short* dst; int j = i;
    if (j < na4){ src = a; dst = oa; }
    else if (j < na4 + nb4){ j -= na4; src = b; dst = ob; }
    else { j -= na4 + nb4; src = c; dst = oc; }
    float4 f = *(const float4*)(src + (long long)j*4);
    us4 v; v.x=f2bf(f.x); v.y=f2bf(f.y); v.z=f2bf(f.z); v.w=f2bf(f.w);
    *(us4*)(dst + (long long)j*4) = v;
  }
}

// ---- transpose-convert z: f32 [10000][128] -> bf16 [128][10048] ----
__global__ void k_tconv_z(const float* __restrict__ z, unsigned short* __restrict__ o){
  __shared__ unsigned short t[64][65];
  const int rb = blockIdx.x*64, cb = blockIdx.y*64;
  #pragma unroll
  for (int it = 0; it < 4; ++it){
    int idx = it*256 + threadIdx.x;
    int r = idx >> 4, c4 = (idx & 15) * 4;
    float4 f = {0.f,0.f,0.f,0.f};
    if (rb + r < 10000) f = *(const float4*)(z + (long long)(rb+r)*128 + cb + c4);
    t[c4+0][r] = f2bf(f.x); t[c4+1][r] = f2bf(f.y);
    t[c4+2][r] = f2bf(f.z); t[c4+3][r] = f2bf(f.w);
  }
  __syncthreads();
  #pragma unroll
  for (int it = 0; it < 4; ++it){
    int idx = it*256 + threadIdx.x;
    int ro = idx >> 4, co4 = (idx & 15) * 4;
    us4 v; v.x=t[ro][co4]; v.y=t[ro][co4+1]; v.z=t[ro][co4+2]; v.w=t[ro][co4+3];
    *(us4*)(o + (long long)(cb+ro)*10048 + rb + co4) = v;
  }
}

// ---- transpose bf16: [10000][256] -> [256][10048] ----
__global__ void k_t_bf16(const unsigned short* __restrict__ in, unsigned short* __restrict__ o){
  __shared__ unsigned short t[64][65];
  const int rb = blockIdx.x*64, cb = blockIdx.y*64;
  #pragma unroll
  for (int it = 0; it < 4; ++it){
    int idx = it*256 + threadIdx.x;
    int r = idx >> 4, c4 = (idx & 15) * 4;
    us4 v = {0,0,0,0};
    if (rb + r < 10000) v = *(const us4*)(in + (long long)(rb+r)*256 + cb + c4);
    t[c4+0][r]=v.x; t[c4+1][r]=v.y; t[c4+2][r]=v.z; t[c4+3][r]=v.w;
  }
  __syncthreads();
  #pragma unroll
  for (int it = 0; it < 4; ++it){
    int idx = it*256 + threadIdx.x;
    int ro = idx >> 4, co4 = (idx & 15)*4;
    us4 v; v.x=t[ro][co4]; v.y=t[ro][co4+1]; v.z=t[ro][co4+2]; v.w=t[ro][co4+3];
    *(us4*)(o + (long long)(cb+ro)*10048 + rb + co4) = v;
  }
}

// ================= 8-phase 256x256 GEMM, split-K, deep prefetch =================
// A bf16 [10240][10048]; B bf16 [>=nBase+256][10048]; P f32 [S][10240][ldp]
// 8 waves (2M x 4N), per-wave C = 128x64 (acc[8][4] 16x16 frags).
// LDS: 2 x (A 256x64 | B 256x64) = 128 KB.
// All 8 gl_lds16 of tile kt+1 issued at the HEAD of tile kt (full K-tile of
// lead, ~4 phases of MFMA covering load latency); one counted vmcnt(8)/K-tile.
__global__ __launch_bounds__(512)
void k_gemm8(const unsigned short* __restrict__ A,
             const unsigned short* __restrict__ B,
             float* __restrict__ P, int S, int ldp)
{
  constexpr int LDA = 10048;
  __shared__ unsigned short sm[2][32768];

  const int tid = threadIdx.x;
  const int wid = tid >> 6, l = tid & 63;
  const int wm = wid >> 2, wn = wid & 3;
  const int lr = l & 15, lk = l >> 4;
  const int mBase = blockIdx.x * 256;
  const int nBase = blockIdx.y * 256;
  const int s = blockIdx.z;
  const int kt0 = (157 * s) / S, kt1 = (157 * (s + 1)) / S;

  // Precompute the 8 per-thread staging chunks (global src base + LDS offset).
  // h: 0=A rows 0-127, 1=A rows 128-255, 2=B rows 0-127, 3=B rows 128-255.
  // Linear LDS dst (gl_lds req), inverse-swizzled global source (rule #21).
  const unsigned short* gsrc[8];
  int ldst[8];
  #pragma unroll
  for (int h = 0; h < 4; ++h){
    const unsigned short* base = (h < 2) ? A : B;
    const int rowBase = ((h < 2) ? mBase : nBase) + (h & 1) * 128;
    const int ldsOff = ((h < 2) ? 0 : 16384) + (h & 1) * 8192;
    #pragma unroll
    for (int i = 0; i < 2; ++i){
      int ch = tid + 512 * i;
      int row = ch >> 3, gc = (ch & 7) ^ (row & 7);
      gsrc[h*2+i] = base + (long long)(rowBase + row) * LDA + gc * 8;
      ldst[h*2+i] = ldsOff + ch * 8;
    }
  }
  auto stage_tile = [&](unsigned short* dst, int kt){
    const long long ko = (long long)kt * 64;
    #pragma unroll
    for (int i = 0; i < 8; ++i)
      gl_lds16(gsrc[i] + ko, dst + ldst[i]);
  };

  f32x4 acc[8][4];
  #pragma unroll
  for (int i = 0; i < 8; ++i)
    #pragma unroll
    for (int j = 0; j < 4; ++j){ f32x4 zz = {0.f,0.f,0.f,0.f}; acc[i][j] = zz; }

  stage_tile(&sm[0][0], kt0);

  int cur = 0;
  for (int kt = kt0; kt < kt1; ++kt){
    const bool pf = (kt + 1 < kt1);
    unsigned short* nb = &sm[cur ^ 1][0];
    const unsigned short* sp = &sm[cur][0];

    // head: issue next tile early, then wait for current tile's 8 loads
    if (pf){
      stage_tile(nb, kt + 1);
      __builtin_amdgcn_sched_barrier(0);
      asm volatile("s_waitcnt vmcnt(8)" ::: "memory");
    } else {
      asm volatile("s_waitcnt vmcnt(0)" ::: "memory");
    }
    __builtin_amdgcn_sched_barrier(0);
    __builtin_amdgcn_s_barrier();
    __builtin_amdgcn_sched_barrier(0);

    #pragma unroll
    for (int q = 0; q < 4; ++q){
      const int ih = q >> 1, jh = q & 1;   // quadrant: A-rows half, B-rows half
      short8 af[4][2], bf[2][2];
      #pragma unroll
      for (int ii = 0; ii < 4; ++ii){
        const int row = wm*128 + (ih*4 + ii)*16 + lr;
        #pragma unroll
        for (int ks = 0; ks < 2; ++ks)
          af[ii][ks] = *(const short8*)(sp + row*64 + (((ks*4 + lk) ^ (row & 7)) * 8));
      }
      #pragma unroll
      for (int jj = 0; jj < 2; ++jj){
        const int row = wn*64 + (jh*2 + jj)*16 + lr;
        #pragma unroll
        for (int ks = 0; ks < 2; ++ks)
          bf[jj][ks] = *(const short8*)(sp + 16384 + row*64 + (((ks*4 + lk) ^ (row & 7)) * 8));
      }
      __builtin_amdgcn_s_setprio(1);
      #pragma unroll
      for (int ks = 0; ks < 2; ++ks)
        #pragma unroll
        for (int ii = 0; ii < 4; ++ii)
          #pragma unroll
          for (int jj = 0; jj < 2; ++jj)
            acc[ih*4+ii][jh*2+jj] =
              MFMA16(af[ii][ks], bf[jj][ks], acc[ih*4+ii][jh*2+jj]);
      __builtin_amdgcn_s_setprio(0);
      __builtin_amdgcn_sched_barrier(0);
      __builtin_amdgcn_s_barrier();
      __builtin_amdgcn_sched_barrier(0);
    }
    cur ^= 1;
  }

  float* Pp = P + (long long)s * MROWS * ldp;
  #pragma unroll
  for (int i = 0; i < 8; ++i){
    const int row0 = mBase + wm*128 + i*16 + lk*4;
    #pragma unroll
    for (int j = 0; j < 4; ++j){
      const int col = nBase + wn*64 + j*16 + lr;
      #pragma unroll
      for (int r = 0; r < 4; ++r)
        Pp[(long long)(row0 + r)*ldp + col] = acc[i][j][r];
    }
  }
}

// ---- 2-phase GEMM (kept for the skinny t0 = g@z pass, N=128) ----
template<int BN, int NWM, int NWN>
__global__ __launch_bounds__(256)
void k_gemm(const unsigned short* __restrict__ A,
            const unsigned short* __restrict__ B,
            float* __restrict__ P, int S, int ldp)
{
  constexpr int LDA = 10048;
  constexpr int BM  = 64;
  constexpr int WM = BM / NWM, WN = BN / NWN;
  constexpr int MF = WM / 16, NF = WN / 16;
  constexpr int AE = BM * 64;
  constexpr int BE = BN * 64;
  constexpr int ACH = BM * 8 / 256;
  constexpr int BCH = BN * 8 / 256;

  __shared__ unsigned short sm[2][AE + BE];

  const int tid = threadIdx.x, w = tid >> 6, l = tid & 63;
  const int lr = l & 15, lk = l >> 4, swz = l & 7;
  const int wm = w / NWN, wn = w % NWN;
  const int mBase = blockIdx.x * BM;
  const int nBase = blockIdx.y * BN;
  const int s = blockIdx.z;
  const int kt0 = (157 * s) / S, kt1 = (157 * (s + 1)) / S;

  auto stage = [&](int buf, int kt){
    unsigned short* dst = &sm[buf][0];
    const unsigned short* Ak = A + (long long)kt * 64;
    const unsigned short* Bk = B + (long long)kt * 64;
    #pragma unroll
    for (int i = 0; i < ACH; ++i){
      int c = i * 256 + tid;
      int row = c >> 3, gr = c & 7;
      gl_lds16(Ak + (long long)(mBase + row) * LDA + ((gr ^ (row & 7)) * 8),
               dst + c * 8);
    }
    #pragma unroll
    for (int i = 0; i < BCH; ++i){
      int c = i * 256 + tid;
      int row = c >> 3, gr = c & 7;
      gl_lds16(Bk + (long long)(nBase + row) * LDA + ((gr ^ (row & 7)) * 8),
               dst + AE + c * 8);
    }
  };

  f32x4 acc[MF][NF];
  #pragma unroll
  for (int i = 0; i < MF; ++i)
    #pragma unroll
    for (int j = 0; j < NF; ++j){ f32x4 zz = {0.f,0.f,0.f,0.f}; acc[i][j] = zz; }

  stage(0, kt0);
  int cur = 0;
  for (int kt = kt0; kt < kt1; ++kt){
    __syncthreads();
    if (kt + 1 < kt1) stage(cur ^ 1, kt + 1);
    const unsigned short* sp = &sm[cur][0];
    #pragma unroll
    for (int ks = 0; ks < 2; ++ks){
      short8 a[MF], b[NF];
      #pragma unroll
      for (int i = 0; i < MF; ++i){
        int row = wm * WM + i * 16 + lr;
        a[i] = *(const short8*)(sp + row * 64 + (((4*ks + lk) ^ swz) * 8));
      }
      #pragma unroll
      for (int j = 0; j < NF; ++j){
        int row = wn * WN + j * 16 + lr;
        b[j] = *(const short8*)(sp + AE + row * 64 + (((4*ks + lk) ^ swz) * 8));
      }
      #pragma unroll
      for (int i = 0; i < MF; ++i)
        #pragma unroll
        for (int j = 0; j < NF; ++j)
          acc[i][j] = MFMA16(a[i], b[j], acc[i][j]);
    }
    cur ^= 1;
  }

  float* Pp = P + (long long)s * MROWS * ldp;
  #pragma unroll
  for (int i = 0; i < MF; ++i){
    const int row0 = mBase + wm * WM + i * 16 + lk * 4;
    #pragma unroll
    for (int j = 0; j < NF; ++j){
      const int col = nBase + wn * WN + j * 16 + lr;
      #pragma unroll
      for (int r = 0; r < 4; ++r)
        Pp[(long long)(row0 + r) * ldp + col] = acc[i][j][r];
    }
  }
}

// ---- reduce partials + epilogue (row-major out) ----
// EPI 0: bf16 store; 2: 0.5*sum+0.5*H -> f32
template<int EPI>
__global__ void k_reduce(const float* __restrict__ P, int S, int ldp, int colOff,
                         int lg, void* __restrict__ out, int ldc,
                         const unsigned short* __restrict__ H)
{
  const long long stride = MROWS * ldp;
  const int idx = blockIdx.x * 256 + threadIdx.x;
  const int row = idx >> lg;
  const int c4 = (idx & ((1 << lg) - 1)) * 4;
  const float* p = P + (long long)row * ldp + colOff + c4;
  float4 sv = *(const float4*)p;
  for (int s2 = 1; s2 < S; ++s2){
    float4 t = *(const float4*)(p + (long long)s2 * stride);
    sv.x += t.x; sv.y += t.y; sv.z += t.z; sv.w += t.w;
  }
  if constexpr (EPI == 2){
    us4 h = *(const us4*)(H + (long long)row * 256 + c4);
    sv.x = 0.5f*sv.x + 0.5f*bf2f(h.x);
    sv.y = 0.5f*sv.y + 0.5f*bf2f(h.y);
    sv.z = 0.5f*sv.z + 0.5f*bf2f(h.z);
    sv.w = 0.5f*sv.w + 0.5f*bf2f(h.w);
    *(float4*)((float*)out + (long long)row * ldc + c4) = sv;
  } else {
    us4 o; o.x=f2bf(sv.x); o.y=f2bf(sv.y); o.z=f2bf(sv.z); o.w=f2bf(sv.w);
    *(us4*)((unsigned short*)out + (long long)row * ldc + c4) = o;
  }
}

// ---- fused reduce + APPNP epilogue + TRANSPOSED write ----
// outT[cb+ro][rb+co] = bf16(0.5*sum_s P[s][row][colOff+col] + 0.5*H[row][col])
// grid (157, 4), block 256. Replaces k_reduce<1> + k_t_bf16.
__global__ void k_reduce_T(const float* __restrict__ P, int S, int ldp, int colOff,
                           unsigned short* __restrict__ outT,
                           const unsigned short* __restrict__ H)
{
  __shared__ unsigned short t[64][65];
  const int rb = blockIdx.x*64, cb = blockIdx.y*64;
  const long long stride = MROWS * (long long)ldp;
  #pragma unroll
  for (int it = 0; it < 4; ++it){
    int idx = it*256 + threadIdx.x;
    int r = idx >> 4, c4 = (idx & 15)*4;
    int row = rb + r;
    float4 sv = {0.f,0.f,0.f,0.f};
    if (row < 10000){
      const float* p = P + (long long)row*ldp + colOff + cb + c4;
      sv = *(const float4*)p;
      for (int s2 = 1; s2 < S; ++s2){
        float4 tt = *(const float4*)(p + (long long)s2*stride);
        sv.x += tt.x; sv.y += tt.y; sv.z += tt.z; sv.w += tt.w;
      }
      us4 h = *(const us4*)(H + (long long)row*256 + cb + c4);
      sv.x = 0.5f*sv.x + 0.5f*bf2f(h.x);
      sv.y = 0.5f*sv.y + 0.5f*bf2f(h.y);
      sv.z = 0.5f*sv.z + 0.5f*bf2f(h.z);
      sv.w = 0.5f*sv.w + 0.5f*bf2f(h.w);
    }
    t[c4+0][r] = f2bf(sv.x); t[c4+1][r] = f2bf(sv.y);
    t[c4+2][r] = f2bf(sv.z); t[c4+3][r] = f2bf(sv.w);
  }
  __syncthreads();
  #pragma unroll
  for (int it = 0; it < 4; ++it){
    int idx = it*256 + threadIdx.x;
    int ro = idx >> 4, co4 = (idx & 15)*4;
    us4 v; v.x=t[ro][co4]; v.y=t[ro][co4+1]; v.z=t[ro][co4+2]; v.w=t[ro][co4+3];
    *(us4*)(outT + (long long)(cb+ro)*10048 + rb + co4) = v;
  }
}

// ---- small GEMM: out = act(A @ W^T), A bf16 [10000][KW], W bf16 [NW][KW] ----
// ACT 0: relu->bf16; 1: sigmoid->f32. DONORM: also write out2 = rownorm(out).
template<int NW, int KW, int ACT, int DONORM>
__global__ __launch_bounds__(320)
void k_gemm_small(const unsigned short* __restrict__ A,
                  const unsigned short* __restrict__ W,
                  void* __restrict__ out, unsigned short* __restrict__ out2)
{
  const int tid = threadIdx.x, w = tid >> 6, l = tid & 63;
  const int lr = l & 15, lk = l >> 4;
  const int mBase = blockIdx.x * 80;
  constexpr int NF = NW/16;

  f32x4 acc[NF];
  #pragma unroll
  for (int f = 0; f < NF; ++f){ f32x4 zz = {0.f,0.f,0.f,0.f}; acc[f] = zz; }

  const unsigned short* ap = A + (long long)(mBase + 16*w + lr)*KW + lk*8;
  #pragma unroll
  for (int kc = 0; kc < KW/32; ++kc){
    short8 a = *(const short8*)(ap + kc*32);
    #pragma unroll
    for (int f = 0; f < NF; ++f){
      short8 b = *(const short8*)(W + (long long)(16*f + lr)*KW + kc*32 + lk*8);
      acc[f] = MFMA16(a, b, acc[f]);
    }
  }

  const int row0 = mBase + 16*w + lk*4;
  if constexpr (DONORM){
    // relu in place, then row L2-norm: row (row0+r) spans lanes with same lk
    float ss[4] = {0.f,0.f,0.f,0.f};
    #pragma unroll
    for (int f = 0; f < NF; ++f)
      #pragma unroll
      for (int r = 0; r < 4; ++r){
        float v = fmaxf(acc[f][r], 0.0f);
        acc[f][r] = v;
        ss[r] += v*v;
      }
    #pragma unroll
    for (int r = 0; r < 4; ++r){
      #pragma unroll
      for (int off = 1; off <= 8; off <<= 1)
        ss[r] += __shfl_xor(ss[r], off, 64);
      ss[r] = 1.0f / fmaxf(sqrtf(ss[r]), 1e-12f);
    }
    #pragma unroll
    for (int f = 0; f < NF; ++f){
      const int col = 16*f + lr;
      #pragma unroll
      for (int r = 0; r < 4; ++r){
        const long long idx = (long long)(row0 + r)*NW + col;
        ((unsigned short*)out)[idx] = f2bf(acc[f][r]);
        out2[idx] = f2bf(acc[f][r] * ss[r]);
      }
    }
  } else {
    #pragma unroll
    for (int f = 0; f < NF; ++f){
      const int col = 16*f + lr;
      #pragma unroll
      for (int r = 0; r < 4; ++r){
        const long long idx = (long long)(row0 + r)*NW + col;
        float v = acc[f][r];
        if constexpr (ACT == 0) ((unsigned short*)out)[idx] = f2bf(fmaxf(v, 0.0f));
        else                    ((float*)out)[idx] = 1.0f / (1.0f + expf(-v));
      }
    }
  }
}

extern "C" void kernel_launch(void* const* d_in, const int* in_sizes, int n_in,
                              void* d_out, int out_size, void* d_ws, size_t ws_size,
                              hipStream_t stream)
{
  const float* g   = (const float*)d_in[0];
  const float* z   = (const float*)d_in[1];
  const float* W1  = (const float*)d_in[2];
  const float* W1_ = (const float*)d_in[3];
  const float* W2  = (const float*)d_in[4];

  char* ws = (char*)d_ws;
  size_t off = 0;
  auto alloc = [&](size_t bytes)->void*{
    void* p = ws + off; off += (bytes + 255) & ~(size_t)255; return p;
  };
  unsigned short* g16  = (unsigned short*)alloc(10240ULL*10048*2); // 206 MB
  unsigned short* zT   = (unsigned short*)alloc(128ULL*10048*2);
  unsigned short* W1c  = (unsigned short*)alloc(256ULL*128*2);
  unsigned short* W1_c = (unsigned short*)alloc(256ULL*256*2);
  unsigned short* W2c  = (unsigned short*)alloc(128ULL*256*2);
  unsigned short* tbuf = (unsigned short*)alloc(10000ULL*256*2);   // t0/t1/t2
  unsigned short* Xbuf = (unsigned short*)alloc(10000ULL*256*2);   // z1/z_
  unsigned short* Tbuf = (unsigned short*)alloc(512ULL*10048*2);   // B operand (transposed)
  unsigned short* zn   = (unsigned short*)alloc(10000ULL*256*2);
  float*          P    = (float*)alloc(10240ULL*1536*4);           // 63 MB partials
  (void)ws_size; (void)in_sizes; (void)n_in; (void)out_size;

  float* res  = (float*)d_out;                    // [10000][128]
  float* Zout = (float*)d_out + 10000LL*128;      // [10000][256]

  // conversions
  k_conv_g<<<dim3(2048), dim3(256), 0, stream>>>(g, g16);
  k_tconv_z<<<dim3(157,2), dim3(256), 0, stream>>>(z, zT);
  k_conv_w<<<dim3(120), dim3(256), 0, stream>>>(W1, W1c, 256*128/4,
                                                W1_, W1_c, 256*256/4,
                                                W2, W2c, 128*256/4);

  // t0 = g @ z  (N=128, S=3) -- 2-phase kernel
  k_gemm<128,2,2><<<dim3(157,1,3), dim3(256), 0, stream>>>(g16, zT, P, 3, 128);
  k_reduce<0><<<dim3(1250), dim3(256), 0, stream>>>(P, 3, 128, 0, 5, tbuf, 128, nullptr);
  // z1 = relu(t0 @ W1^T)
  k_gemm_small<256,128,0,0><<<dim3(125), dim3(320), 0, stream>>>(tbuf, W1c, Xbuf, nullptr);
  k_t_bf16<<<dim3(157,4), dim3(256), 0, stream>>>(Xbuf, Tbuf);              // z1^T
  // t1 = g @ z1 (N=256, S=6) -- 8-phase deep
  k_gemm8<<<dim3(40,1,6), dim3(512), 0, stream>>>(g16, Tbuf, P, 6, 256);
  k_reduce<0><<<dim3(2500), dim3(256), 0, stream>>>(P, 6, 256, 0, 6, tbuf, 256, nullptr);
  // z_ = relu(t1 @ W1_^T), zn = rownorm(z_)  (fused)
  k_gemm_small<256,256,0,1><<<dim3(125), dim3(320), 0, stream>>>(tbuf, W1_c, Xbuf, zn);
  k_t_bf16<<<dim3(157,4), dim3(256), 0, stream>>>(Xbuf, Tbuf);              // z_^T
  k_t_bf16<<<dim3(157,4), dim3(256), 0, stream>>>(zn, Tbuf + 256LL*10048);  // zn^T
  // [t2 | g@zn] = g @ [z_ | zn]  (N=512, S=3) -- 8-phase deep
  k_gemm8<<<dim3(40,2,3), dim3(512), 0, stream>>>(g16, Tbuf, P, 3, 512);
  k_reduce<0><<<dim3(2500), dim3(256), 0, stream>>>(P, 3, 512, 0, 6, tbuf, 256, nullptr);
  k_reduce_T<<<dim3(157,4), dim3(256), 0, stream>>>(P, 3, 512, 256, Tbuf, zn); // Z1^T
  // res = sigmoid(t2 @ W2^T) -> f32 d_out
  k_gemm_small<128,256,1,0><<<dim3(125), dim3(320), 0, stream>>>(tbuf, W2c, res, nullptr);
  // Z2^T = T(0.5*(g@Z1) + 0.5*zn)
  k_gemm8<<<dim3(40,1,6), dim3(512), 0, stream>>>(g16, Tbuf, P, 6, 256);
  k_reduce_T<<<dim3(157,4), dim3(256), 0, stream>>>(P, 6, 256, 0, Tbuf, zn);   // Z2^T
  // Z3 = 0.5*(g@Z2) + 0.5*zn -> f32 d_out
  k_gemm8<<<dim3(40,1,6), dim3(512), 0, stream>>>(g16, Tbuf, P, 6, 256);
  k_reduce<2><<<dim3(2500), dim3(256), 0, stream>>>(P, 6, 256, 0, 6, Zout, 256, zn);
}

// Round 5
// 643.423 us; speedup vs baseline: 1.0370x; 1.0370x over previous
//
#include <hip/hip_runtime.h>
#include <stdint.h>

typedef __attribute__((ext_vector_type(8))) short short8;
typedef __attribute__((ext_vector_type(4))) float f32x4;
typedef __attribute__((ext_vector_type(4))) unsigned short us4;

#define MFMA16(a,b,c) __builtin_amdgcn_mfma_f32_16x16x32_bf16((a),(b),(c),0,0,0)

static __device__ __forceinline__ float bf2f(unsigned short u){
  union { float f; unsigned int i; } c; c.i = ((unsigned int)u) << 16; return c.f;
}
static __device__ __forceinline__ unsigned short f2bf(float f){
  union { float f; unsigned int i; } c; c.f = f;
  unsigned int x = c.i;
  unsigned int r = x + 0x7fffu + ((x >> 16) & 1u);
  return (unsigned short)(r >> 16);
}

typedef const __attribute__((address_space(1))) void cg_void;
typedef __attribute__((address_space(3))) void lds_void;
static __device__ __forceinline__ void gl_lds16(const void* g, void* l){
  __builtin_amdgcn_global_load_lds((cg_void*)g, (lds_void*)l, 16, 0, 0);
}

#define MROWS 10240LL   // padded M rows for 256-tile GEMM

// ---- convert g: f32 [10000][10000] -> bf16 [10240][10048], pad rows+cols zero ----
__global__ void k_conv_g(const float* __restrict__ g, unsigned short* __restrict__ o){
  const int CH = 2512; // 10048/4 chunks per row
  const long long total = 10240LL * CH;
  for (long long i = (long long)blockIdx.x*blockDim.x + threadIdx.x; i < total;
       i += (long long)gridDim.x*blockDim.x){
    int r = (int)(i / CH);
    int c4 = (int)(i % CH) * 4;
    us4 v = {0,0,0,0};
    if (r < 10000 && c4 < 10000){
      float4 f = *(const float4*)(g + (long long)r*10000 + c4);
      v.x = f2bf(f.x); v.y = f2bf(f.y); v.z = f2bf(f.z); v.w = f2bf(f.w);
    }
    *(us4*)(o + (long long)r*10048 + c4) = v;
  }
}

// ---- convert the 3 weight matrices in one launch ----
__global__ void k_conv_w(const float* __restrict__ a, unsigned short* __restrict__ oa, int na4,
                         const float* __restrict__ b, unsigned short* __restrict__ ob, int nb4,
                         const float* __restrict__ c, unsigned short* __restrict__ oc, int nc4){
  for (int i = blockIdx.x*blockDim.x + threadIdx.x; i < na4 + nb4 + nc4;
       i += gridDim.x*blockDim.x){
    const float* src; unsigned short* dst; int j = i;
    if (j < na4){ src = a; dst = oa; }
    else if (j < na4 + nb4){ j -= na4; src = b; dst = ob; }
    else { j -= na4 + nb4; src = c; dst = oc; }
    float4 f = *(const float4*)(src + (long long)j*4);
    us4 v; v.x=f2bf(f.x); v.y=f2bf(f.y); v.z=f2bf(f.z); v.w=f2bf(f.w);
    *(us4*)(dst + (long long)j*4) = v;
  }
}

// ---- transpose-convert z: f32 [10000][128] -> bf16 [128][10048] ----
__global__ void k_tconv_z(const float* __restrict__ z, unsigned short* __restrict__ o){
  __shared__ unsigned short t[64][65];
  const int rb = blockIdx.x*64, cb = blockIdx.y*64;
  #pragma unroll
  for (int it = 0; it < 4; ++it){
    int idx = it*256 + threadIdx.x;
    int r = idx >> 4, c4 = (idx & 15) * 4;
    float4 f = {0.f,0.f,0.f,0.f};
    if (rb + r < 10000) f = *(const float4*)(z + (long long)(rb+r)*128 + cb + c4);
    t[c4+0][r] = f2bf(f.x); t[c4+1][r] = f2bf(f.y);
    t[c4+2][r] = f2bf(f.z); t[c4+3][r] = f2bf(f.w);
  }
  __syncthreads();
  #pragma unroll
  for (int it = 0; it < 4; ++it){
    int idx = it*256 + threadIdx.x;
    int ro = idx >> 4, co4 = (idx & 15) * 4;
    us4 v; v.x=t[ro][co4]; v.y=t[ro][co4+1]; v.z=t[ro][co4+2]; v.w=t[ro][co4+3];
    *(us4*)(o + (long long)(cb+ro)*10048 + rb + co4) = v;
  }
}

// ---- transpose bf16: [10000][256] -> [256][10048] ----
__global__ void k_t_bf16(const unsigned short* __restrict__ in, unsigned short* __restrict__ o){
  __shared__ unsigned short t[64][65];
  const int rb = blockIdx.x*64, cb = blockIdx.y*64;
  #pragma unroll
  for (int it = 0; it < 4; ++it){
    int idx = it*256 + threadIdx.x;
    int r = idx >> 4, c4 = (idx & 15) * 4;
    us4 v = {0,0,0,0};
    if (rb + r < 10000) v = *(const us4*)(in + (long long)(rb+r)*256 + cb + c4);
    t[c4+0][r]=v.x; t[c4+1][r]=v.y; t[c4+2][r]=v.z; t[c4+3][r]=v.w;
  }
  __syncthreads();
  #pragma unroll
  for (int it = 0; it < 4; ++it){
    int idx = it*256 + threadIdx.x;
    int ro = idx >> 4, co4 = (idx & 15)*4;
    us4 v; v.x=t[ro][co4]; v.y=t[ro][co4+1]; v.z=t[ro][co4+2]; v.w=t[ro][co4+3];
    *(us4*)(o + (long long)(cb+ro)*10048 + rb + co4) = v;
  }
}

// ================= 256x256 GEMM, split-K, deep prefetch, min-LDS-reads ======
// A bf16 [10240][10048]; B bf16 [>=nBase+256][10048]; P f32 [S][10240][ldp]
// 8 waves (2M x 4N), per-wave C = 128x64 (acc[8][4] 16x16 frags).
// LDS: 2 x (A 256x64 | B 256x64) = 128 KB.
// All 8 gl_lds16 of tile kt+1 issued at the HEAD of tile kt (full K-tile of
// MFMA covers load latency); one counted vmcnt(8) + 2 barriers per K-tile.
// Fragments read ONCE per K-tile: 8 B-reads + 16 A-reads = 24 ds_read_b128
// per 64 MFMA/wave (384 B/MFMA, m201 ratio).
__global__ __launch_bounds__(512)
void k_gemm8(const unsigned short* __restrict__ A,
             const unsigned short* __restrict__ B,
             float* __restrict__ P, int S, int ldp)
{
  constexpr int LDA = 10048;
  __shared__ unsigned short sm[2][32768];

  const int tid = threadIdx.x;
  const int wid = tid >> 6, l = tid & 63;
  const int wm = wid >> 2, wn = wid & 3;
  const int lr = l & 15, lk = l >> 4;
  const int mBase = blockIdx.x * 256;
  const int nBase = blockIdx.y * 256;
  const int s = blockIdx.z;
  const int kt0 = (157 * s) / S, kt1 = (157 * (s + 1)) / S;

  // Precompute the 8 per-thread staging chunks (global src base + LDS offset).
  // h: 0=A rows 0-127, 1=A rows 128-255, 2=B rows 0-127, 3=B rows 128-255.
  // Linear LDS dst (gl_lds req), inverse-swizzled global source (rule #21).
  const unsigned short* gsrc[8];
  int ldst[8];
  #pragma unroll
  for (int h = 0; h < 4; ++h){
    const unsigned short* base = (h < 2) ? A : B;
    const int rowBase = ((h < 2) ? mBase : nBase) + (h & 1) * 128;
    const int ldsOff = ((h < 2) ? 0 : 16384) + (h & 1) * 8192;
    #pragma unroll
    for (int i = 0; i < 2; ++i){
      int ch = tid + 512 * i;
      int row = ch >> 3, gc = (ch & 7) ^ (row & 7);
      gsrc[h*2+i] = base + (long long)(rowBase + row) * LDA + gc * 8;
      ldst[h*2+i] = ldsOff + ch * 8;
    }
  }
  auto stage_tile = [&](unsigned short* dst, int kt){
    const long long ko = (long long)kt * 64;
    #pragma unroll
    for (int i = 0; i < 8; ++i)
      gl_lds16(gsrc[i] + ko, dst + ldst[i]);
  };

  f32x4 acc[8][4];
  #pragma unroll
  for (int i = 0; i < 8; ++i)
    #pragma unroll
    for (int j = 0; j < 4; ++j){ f32x4 zz = {0.f,0.f,0.f,0.f}; acc[i][j] = zz; }

  stage_tile(&sm[0][0], kt0);

  int cur = 0;
  for (int kt = kt0; kt < kt1; ++kt){
    const bool pf = (kt + 1 < kt1);
    unsigned short* nb = &sm[cur ^ 1][0];
    const unsigned short* sp = &sm[cur][0];

    // head: issue next tile early, then wait for current tile's 8 loads
    if (pf){
      stage_tile(nb, kt + 1);
      __builtin_amdgcn_sched_barrier(0);
      asm volatile("s_waitcnt vmcnt(8)" ::: "memory");
    } else {
      asm volatile("s_waitcnt vmcnt(0)" ::: "memory");
    }
    __builtin_amdgcn_sched_barrier(0);
    __builtin_amdgcn_s_barrier();
    __builtin_amdgcn_sched_barrier(0);

    // B fragments: read once per K-tile (8 x ds_read_b128)
    short8 bfr[4][2];
    #pragma unroll
    for (int jj = 0; jj < 4; ++jj){
      const int row = wn*64 + jj*16 + lr;
      #pragma unroll
      for (int ks = 0; ks < 2; ++ks)
        bfr[jj][ks] = *(const short8*)(sp + 16384 + row*64 + (((ks*4 + lk) ^ (row & 7)) * 8));
    }
    // A halves: read once each (8 x ds_read_b128), 32 MFMA per half
    #pragma unroll
    for (int ih = 0; ih < 2; ++ih){
      short8 af[4][2];
      #pragma unroll
      for (int ii = 0; ii < 4; ++ii){
        const int row = wm*128 + ih*64 + ii*16 + lr;
        #pragma unroll
        for (int ks = 0; ks < 2; ++ks)
          af[ii][ks] = *(const short8*)(sp + row*64 + (((ks*4 + lk) ^ (row & 7)) * 8));
      }
      __builtin_amdgcn_s_setprio(1);
      #pragma unroll
      for (int ks = 0; ks < 2; ++ks)
        #pragma unroll
        for (int ii = 0; ii < 4; ++ii)
          #pragma unroll
          for (int jj = 0; jj < 4; ++jj)
            acc[ih*4+ii][jj] = MFMA16(af[ii][ks], bfr[jj][ks], acc[ih*4+ii][jj]);
      __builtin_amdgcn_s_setprio(0);
    }
    __builtin_amdgcn_sched_barrier(0);
    __builtin_amdgcn_s_barrier();
    __builtin_amdgcn_sched_barrier(0);
    cur ^= 1;
  }

  float* Pp = P + (long long)s * MROWS * ldp;
  #pragma unroll
  for (int i = 0; i < 8; ++i){
    const int row0 = mBase + wm*128 + i*16 + lk*4;
    #pragma unroll
    for (int j = 0; j < 4; ++j){
      const int col = nBase + wn*64 + j*16 + lr;
      #pragma unroll
      for (int r = 0; r < 4; ++r)
        Pp[(long long)(row0 + r)*ldp + col] = acc[i][j][r];
    }
  }
}

// ---- 2-phase GEMM (kept for the skinny t0 = g@z pass, N=128) ----
template<int BN, int NWM, int NWN>
__global__ __launch_bounds__(256)
void k_gemm(const unsigned short* __restrict__ A,
            const unsigned short* __restrict__ B,
            float* __restrict__ P, int S, int ldp)
{
  constexpr int LDA = 10048;
  constexpr int BM  = 64;
  constexpr int WM = BM / NWM, WN = BN / NWN;
  constexpr int MF = WM / 16, NF = WN / 16;
  constexpr int AE = BM * 64;
  constexpr int BE = BN * 64;
  constexpr int ACH = BM * 8 / 256;
  constexpr int BCH = BN * 8 / 256;

  __shared__ unsigned short sm[2][AE + BE];

  const int tid = threadIdx.x, w = tid >> 6, l = tid & 63;
  const int lr = l & 15, lk = l >> 4, swz = l & 7;
  const int wm = w / NWN, wn = w % NWN;
  const int mBase = blockIdx.x * BM;
  const int nBase = blockIdx.y * BN;
  const int s = blockIdx.z;
  const int kt0 = (157 * s) / S, kt1 = (157 * (s + 1)) / S;

  auto stage = [&](int buf, int kt){
    unsigned short* dst = &sm[buf][0];
    const unsigned short* Ak = A + (long long)kt * 64;
    const unsigned short* Bk = B + (long long)kt * 64;
    #pragma unroll
    for (int i = 0; i < ACH; ++i){
      int c = i * 256 + tid;
      int row = c >> 3, gr = c & 7;
      gl_lds16(Ak + (long long)(mBase + row) * LDA + ((gr ^ (row & 7)) * 8),
               dst + c * 8);
    }
    #pragma unroll
    for (int i = 0; i < BCH; ++i){
      int c = i * 256 + tid;
      int row = c >> 3, gr = c & 7;
      gl_lds16(Bk + (long long)(nBase + row) * LDA + ((gr ^ (row & 7)) * 8),
               dst + AE + c * 8);
    }
  };

  f32x4 acc[MF][NF];
  #pragma unroll
  for (int i = 0; i < MF; ++i)
    #pragma unroll
    for (int j = 0; j < NF; ++j){ f32x4 zz = {0.f,0.f,0.f,0.f}; acc[i][j] = zz; }

  stage(0, kt0);
  int cur = 0;
  for (int kt = kt0; kt < kt1; ++kt){
    __syncthreads();
    if (kt + 1 < kt1) stage(cur ^ 1, kt + 1);
    const unsigned short* sp = &sm[cur][0];
    #pragma unroll
    for (int ks = 0; ks < 2; ++ks){
      short8 a[MF], b[NF];
      #pragma unroll
      for (int i = 0; i < MF; ++i){
        int row = wm * WM + i * 16 + lr;
        a[i] = *(const short8*)(sp + row * 64 + (((4*ks + lk) ^ swz) * 8));
      }
      #pragma unroll
      for (int j = 0; j < NF; ++j){
        int row = wn * WN + j * 16 + lr;
        b[j] = *(const short8*)(sp + AE + row * 64 + (((4*ks + lk) ^ swz) * 8));
      }
      #pragma unroll
      for (int i = 0; i < MF; ++i)
        #pragma unroll
        for (int j = 0; j < NF; ++j)
          acc[i][j] = MFMA16(a[i], b[j], acc[i][j]);
    }
    cur ^= 1;
  }

  float* Pp = P + (long long)s * MROWS * ldp;
  #pragma unroll
  for (int i = 0; i < MF; ++i){
    const int row0 = mBase + wm * WM + i * 16 + lk * 4;
    #pragma unroll
    for (int j = 0; j < NF; ++j){
      const int col = nBase + wn * WN + j * 16 + lr;
      #pragma unroll
      for (int r = 0; r < 4; ++r)
        Pp[(long long)(row0 + r) * ldp + col] = acc[i][j][r];
    }
  }
}

// ---- reduce partials + epilogue (row-major out) ----
// EPI 0: bf16 store; 2: 0.5*sum+0.5*H -> f32
template<int EPI>
__global__ void k_reduce(const float* __restrict__ P, int S, int ldp, int colOff,
                         int lg, void* __restrict__ out, int ldc,
                         const unsigned short* __restrict__ H)
{
  const long long stride = MROWS * ldp;
  const int idx = blockIdx.x * 256 + threadIdx.x;
  const int row = idx >> lg;
  const int c4 = (idx & ((1 << lg) - 1)) * 4;
  const float* p = P + (long long)row * ldp + colOff + c4;
  float4 sv = *(const float4*)p;
  for (int s2 = 1; s2 < S; ++s2){
    float4 t = *(const float4*)(p + (long long)s2 * stride);
    sv.x += t.x; sv.y += t.y; sv.z += t.z; sv.w += t.w;
  }
  if constexpr (EPI == 2){
    us4 h = *(const us4*)(H + (long long)row * 256 + c4);
    sv.x = 0.5f*sv.x + 0.5f*bf2f(h.x);
    sv.y = 0.5f*sv.y + 0.5f*bf2f(h.y);
    sv.z = 0.5f*sv.z + 0.5f*bf2f(h.z);
    sv.w = 0.5f*sv.w + 0.5f*bf2f(h.w);
    *(float4*)((float*)out + (long long)row * ldc + c4) = sv;
  } else {
    us4 o; o.x=f2bf(sv.x); o.y=f2bf(sv.y); o.z=f2bf(sv.z); o.w=f2bf(sv.w);
    *(us4*)((unsigned short*)out + (long long)row * ldc + c4) = o;
  }
}

// ---- fused reduce + APPNP epilogue + TRANSPOSED write ----
// outT[cb+ro][rb+co] = bf16(0.5*sum_s P[s][row][colOff+col] + 0.5*H[row][col])
// grid (157, 4), block 256. Replaces k_reduce<1> + k_t_bf16.
__global__ void k_reduce_T(const float* __restrict__ P, int S, int ldp, int colOff,
                           unsigned short* __restrict__ outT,
                           const unsigned short* __restrict__ H)
{
  __shared__ unsigned short t[64][65];
  const int rb = blockIdx.x*64, cb = blockIdx.y*64;
  const long long stride = MROWS * (long long)ldp;
  #pragma unroll
  for (int it = 0; it < 4; ++it){
    int idx = it*256 + threadIdx.x;
    int r = idx >> 4, c4 = (idx & 15)*4;
    int row = rb + r;
    float4 sv = {0.f,0.f,0.f,0.f};
    if (row < 10000){
      const float* p = P + (long long)row*ldp + colOff + cb + c4;
      sv = *(const float4*)p;
      for (int s2 = 1; s2 < S; ++s2){
        float4 tt = *(const float4*)(p + (long long)s2*stride);
        sv.x += tt.x; sv.y += tt.y; sv.z += tt.z; sv.w += tt.w;
      }
      us4 h = *(const us4*)(H + (long long)row*256 + cb + c4);
      sv.x = 0.5f*sv.x + 0.5f*bf2f(h.x);
      sv.y = 0.5f*sv.y + 0.5f*bf2f(h.y);
      sv.z = 0.5f*sv.z + 0.5f*bf2f(h.z);
      sv.w = 0.5f*sv.w + 0.5f*bf2f(h.w);
    }
    t[c4+0][r] = f2bf(sv.x); t[c4+1][r] = f2bf(sv.y);
    t[c4+2][r] = f2bf(sv.z); t[c4+3][r] = f2bf(sv.w);
  }
  __syncthreads();
  #pragma unroll
  for (int it = 0; it < 4; ++it){
    int idx = it*256 + threadIdx.x;
    int ro = idx >> 4, co4 = (idx & 15)*4;
    us4 v; v.x=t[ro][co4]; v.y=t[ro][co4+1]; v.z=t[ro][co4+2]; v.w=t[ro][co4+3];
    *(us4*)(outT + (long long)(cb+ro)*10048 + rb + co4) = v;
  }
}

// ---- small GEMM: out = act(A @ W^T), A bf16 [10000][KW], W bf16 [NW][KW] ----
// ACT 0: relu->bf16; 1: sigmoid->f32. DONORM: also write out2 = rownorm(out).
template<int NW, int KW, int ACT, int DONORM>
__global__ __launch_bounds__(320)
void k_gemm_small(const unsigned short* __restrict__ A,
                  const unsigned short* __restrict__ W,
                  void* __restrict__ out, unsigned short* __restrict__ out2)
{
  const int tid = threadIdx.x, w = tid >> 6, l = tid & 63;
  const int lr = l & 15, lk = l >> 4;
  const int mBase = blockIdx.x * 80;
  constexpr int NF = NW/16;

  f32x4 acc[NF];
  #pragma unroll
  for (int f = 0; f < NF; ++f){ f32x4 zz = {0.f,0.f,0.f,0.f}; acc[f] = zz; }

  const unsigned short* ap = A + (long long)(mBase + 16*w + lr)*KW + lk*8;
  #pragma unroll
  for (int kc = 0; kc < KW/32; ++kc){
    short8 a = *(const short8*)(ap + kc*32);
    #pragma unroll
    for (int f = 0; f < NF; ++f){
      short8 b = *(const short8*)(W + (long long)(16*f + lr)*KW + kc*32 + lk*8);
      acc[f] = MFMA16(a, b, acc[f]);
    }
  }

  const int row0 = mBase + 16*w + lk*4;
  if constexpr (DONORM){
    // relu in place, then row L2-norm: row (row0+r) spans lanes with same lk
    float ss[4] = {0.f,0.f,0.f,0.f};
    #pragma unroll
    for (int f = 0; f < NF; ++f)
      #pragma unroll
      for (int r = 0; r < 4; ++r){
        float v = fmaxf(acc[f][r], 0.0f);
        acc[f][r] = v;
        ss[r] += v*v;
      }
    #pragma unroll
    for (int r = 0; r < 4; ++r){
      #pragma unroll
      for (int off = 1; off <= 8; off <<= 1)
        ss[r] += __shfl_xor(ss[r], off, 64);
      ss[r] = 1.0f / fmaxf(sqrtf(ss[r]), 1e-12f);
    }
    #pragma unroll
    for (int f = 0; f < NF; ++f){
      const int col = 16*f + lr;
      #pragma unroll
      for (int r = 0; r < 4; ++r){
        const long long idx = (long long)(row0 + r)*NW + col;
        ((unsigned short*)out)[idx] = f2bf(acc[f][r]);
        out2[idx] = f2bf(acc[f][r] * ss[r]);
      }
    }
  } else {
    #pragma unroll
    for (int f = 0; f < NF; ++f){
      const int col = 16*f + lr;
      #pragma unroll
      for (int r = 0; r < 4; ++r){
        const long long idx = (long long)(row0 + r)*NW + col;
        float v = acc[f][r];
        if constexpr (ACT == 0) ((unsigned short*)out)[idx] = f2bf(fmaxf(v, 0.0f));
        else                    ((float*)out)[idx] = 1.0f / (1.0f + expf(-v));
      }
    }
  }
}

extern "C" void kernel_launch(void* const* d_in, const int* in_sizes, int n_in,
                              void* d_out, int out_size, void* d_ws, size_t ws_size,
                              hipStream_t stream)
{
  const float* g   = (const float*)d_in[0];
  const float* z   = (const float*)d_in[1];
  const float* W1  = (const float*)d_in[2];
  const float* W1_ = (const float*)d_in[3];
  const float* W2  = (const float*)d_in[4];

  char* ws = (char*)d_ws;
  size_t off = 0;
  auto alloc = [&](size_t bytes)->void*{
    void* p = ws + off; off += (bytes + 255) & ~(size_t)255; return p;
  };
  unsigned short* g16  = (unsigned short*)alloc(10240ULL*10048*2); // 206 MB
  unsigned short* zT   = (unsigned short*)alloc(128ULL*10048*2);
  unsigned short* W1c  = (unsigned short*)alloc(256ULL*128*2);
  unsigned short* W1_c = (unsigned short*)alloc(256ULL*256*2);
  unsigned short* W2c  = (unsigned short*)alloc(128ULL*256*2);
  unsigned short* tbuf = (unsigned short*)alloc(10000ULL*256*2);   // t0/t1/t2
  unsigned short* Xbuf = (unsigned short*)alloc(10000ULL*256*2);   // z1/z_
  unsigned short* Tbuf = (unsigned short*)alloc(512ULL*10048*2);   // B operand (transposed)
  unsigned short* zn   = (unsigned short*)alloc(10000ULL*256*2);
  float*          P    = (float*)alloc(10240ULL*1536*4);           // 63 MB partials
  (void)ws_size; (void)in_sizes; (void)n_in; (void)out_size;

  float* res  = (float*)d_out;                    // [10000][128]
  float* Zout = (float*)d_out + 10000LL*128;      // [10000][256]

  // conversions
  k_conv_g<<<dim3(2048), dim3(256), 0, stream>>>(g, g16);
  k_tconv_z<<<dim3(157,2), dim3(256), 0, stream>>>(z, zT);
  k_conv_w<<<dim3(120), dim3(256), 0, stream>>>(W1, W1c, 256*128/4,
                                                W1_, W1_c, 256*256/4,
                                                W2, W2c, 128*256/4);

  // t0 = g @ z  (N=128, S=3) -- 2-phase kernel
  k_gemm<128,2,2><<<dim3(157,1,3), dim3(256), 0, stream>>>(g16, zT, P, 3, 128);
  k_reduce<0><<<dim3(1250), dim3(256), 0, stream>>>(P, 3, 128, 0, 5, tbuf, 128, nullptr);
  // z1 = relu(t0 @ W1^T)
  k_gemm_small<256,128,0,0><<<dim3(125), dim3(320), 0, stream>>>(tbuf, W1c, Xbuf, nullptr);
  k_t_bf16<<<dim3(157,4), dim3(256), 0, stream>>>(Xbuf, Tbuf);              // z1^T
  // t1 = g @ z1 (N=256, S=6)
  k_gemm8<<<dim3(40,1,6), dim3(512), 0, stream>>>(g16, Tbuf, P, 6, 256);
  k_reduce<0><<<dim3(2500), dim3(256), 0, stream>>>(P, 6, 256, 0, 6, tbuf, 256, nullptr);
  // z_ = relu(t1 @ W1_^T), zn = rownorm(z_)  (fused)
  k_gemm_small<256,256,0,1><<<dim3(125), dim3(320), 0, stream>>>(tbuf, W1_c, Xbuf, zn);
  k_t_bf16<<<dim3(157,4), dim3(256), 0, stream>>>(Xbuf, Tbuf);              // z_^T
  k_t_bf16<<<dim3(157,4), dim3(256), 0, stream>>>(zn, Tbuf + 256LL*10048);  // zn^T
  // [t2 | g@zn] = g @ [z_ | zn]  (N=512, S=3)
  k_gemm8<<<dim3(40,2,3), dim3(512), 0, stream>>>(g16, Tbuf, P, 3, 512);
  k_reduce<0><<<dim3(2500), dim3(256), 0, stream>>>(P, 3, 512, 0, 6, tbuf, 256, nullptr);
  k_reduce_T<<<dim3(157,4), dim3(256), 0, stream>>>(P, 3, 512, 256, Tbuf, zn); // Z1^T
  // res = sigmoid(t2 @ W2^T) -> f32 d_out
  k_gemm_small<128,256,1,0><<<dim3(125), dim3(320), 0, stream>>>(tbuf, W2c, res, nullptr);
  // Z2^T = T(0.5*(g@Z1) + 0.5*zn)
  k_gemm8<<<dim3(40,1,6), dim3(512), 0, stream>>>(g16, Tbuf, P, 6, 256);
  k_reduce_T<<<dim3(157,4), dim3(256), 0, stream>>>(P, 6, 256, 0, Tbuf, zn);   // Z2^T
  // Z3 = 0.5*(g@Z2) + 0.5*zn -> f32 d_out
  k_gemm8<<<dim3(40,1,6), dim3(512), 0, stream>>>(g16, Tbuf, P, 6, 256);
  k_reduce<2><<<dim3(2500), dim3(256), 0, stream>>>(P, 6, 256, 0, 6, Zout, 256, zn);
}

// Round 6
// 558.657 us; speedup vs baseline: 1.1944x; 1.1517x over previous
//
#include <hip/hip_runtime.h>
#include <stdint.h>

typedef __attribute__((ext_vector_type(8))) short short8;
typedef __attribute__((ext_vector_type(4))) float f32x4;
typedef __attribute__((ext_vector_type(4))) unsigned short us4;

#define MFMA16(a,b,c) __builtin_amdgcn_mfma_f32_16x16x32_bf16((a),(b),(c),0,0,0)

static __device__ __forceinline__ float bf2f(unsigned short u){
  union { float f; unsigned int i; } c; c.i = ((unsigned int)u) << 16; return c.f;
}
static __device__ __forceinline__ unsigned short f2bf(float f){
  union { float f; unsigned int i; } c; c.f = f;
  unsigned int x = c.i;
  unsigned int r = x + 0x7fffu + ((x >> 16) & 1u);
  return (unsigned short)(r >> 16);
}
static __device__ __forceinline__ short8 pack8(const float* v){
  short8 r;
  #pragma unroll
  for (int i = 0; i < 8; ++i) r[i] = (short)f2bf(v[i]);
  return r;
}

typedef const __attribute__((address_space(1))) void cg_void;
typedef __attribute__((address_space(3))) void lds_void;
static __device__ __forceinline__ void gl_lds16(const void* g, void* l){
  __builtin_amdgcn_global_load_lds((cg_void*)g, (lds_void*)l, 16, 0, 0);
}

#define MROWS 10240LL   // padded M rows for 256-tile GEMM
#define LDA   10048

// ---- one-time zero fill: g16 tail rows (10048..10239) + Tbuf pad cols ----
__global__ void k_zero(unsigned short* __restrict__ g16, unsigned short* __restrict__ Tbuf){
  const long long i0 = (long long)blockIdx.x*256 + threadIdx.x;
  const long long NG = 192LL*LDA/8;
  short8 z = {0,0,0,0,0,0,0,0};
  for (long long c = i0; c < NG; c += (long long)gridDim.x*256)
    *(short8*)(g16 + 10048LL*LDA + c*8) = z;
  for (long long c = i0; c < 512*6; c += (long long)gridDim.x*256){
    int row = (int)(c/6), k = (int)(c%6);
    *(short8*)(Tbuf + (long long)row*LDA + 10000 + k*8) = z;
  }
}

// ---- convert the 3 weight matrices in one launch ----
__global__ void k_conv_w(const float* __restrict__ a, unsigned short* __restrict__ oa, int na4,
                         const float* __restrict__ b, unsigned short* __restrict__ ob, int nb4,
                         const float* __restrict__ c, unsigned short* __restrict__ oc, int nc4){
  for (int i = blockIdx.x*blockDim.x + threadIdx.x; i < na4 + nb4 + nc4;
       i += gridDim.x*blockDim.x){
    const float* src; unsigned short* dst; int j = i;
    if (j < na4){ src = a; dst = oa; }
    else if (j < na4 + nb4){ j -= na4; src = b; dst = ob; }
    else { j -= na4 + nb4; src = c; dst = oc; }
    float4 f = *(const float4*)(src + (long long)j*4);
    us4 v; v.x=f2bf(f.x); v.y=f2bf(f.y); v.z=f2bf(f.z); v.w=f2bf(f.w);
    *(us4*)(dst + (long long)j*4) = v;
  }
}

// ---- transpose-convert z: f32 [10000][128] -> bf16 [128][10048] ----
__global__ void k_tconv_z(const float* __restrict__ z, unsigned short* __restrict__ o){
  __shared__ unsigned short t[64][65];
  const int rb = blockIdx.x*64, cb = blockIdx.y*64;
  #pragma unroll
  for (int it = 0; it < 4; ++it){
    int idx = it*256 + threadIdx.x;
    int r = idx >> 4, c4 = (idx & 15) * 4;
    float4 f = {0.f,0.f,0.f,0.f};
    if (rb + r < 10000) f = *(const float4*)(z + (long long)(rb+r)*128 + cb + c4);
    t[c4+0][r] = f2bf(f.x); t[c4+1][r] = f2bf(f.y);
    t[c4+2][r] = f2bf(f.z); t[c4+3][r] = f2bf(f.w);
  }
  __syncthreads();
  #pragma unroll
  for (int it = 0; it < 4; ++it){
    int idx = it*256 + threadIdx.x;
    int ro = idx >> 4, co4 = (idx & 15) * 4;
    us4 v; v.x=t[ro][co4]; v.y=t[ro][co4+1]; v.z=t[ro][co4+2]; v.w=t[ro][co4+3];
    *(us4*)(o + (long long)(cb+ro)*LDA + rb + co4) = v;
  }
}

// ================= fused t0: reads f32 g, writes g16 bf16 + t0 partials ======
// BM=64, BN=128, BK=64, 4 waves (2M x 2N), per-wave 32x64. A reg-staged with
// f32->bf16 convert (g16 written as side effect); B via gl_lds from zT.
__global__ __launch_bounds__(256)
void k_gemm_t0(const float* __restrict__ g, const unsigned short* __restrict__ zT,
               unsigned short* __restrict__ g16, unsigned short* __restrict__ P, int S)
{
  constexpr int ldp = 128;
  __shared__ unsigned short sm[2][(64+128)*64];
  const int tid = threadIdx.x, w = tid >> 6, l = tid & 63;
  const int lr = l & 15, lk = l >> 4;
  const int wm = w >> 1, wn = w & 1;
  const int mBase = blockIdx.x * 64;
  const int s = blockIdx.z;
  const int kt0 = (157*s)/S, kt1 = (157*(s+1))/S;

  int arow[2], acol8[2];
  #pragma unroll
  for (int i = 0; i < 2; ++i){
    int ch = tid + 256*i;
    int row = ch >> 3, gr = ch & 7;
    arow[i] = row; acol8[i] = (gr ^ (row & 7)) * 8;
  }
  float fA[2][8];
  auto loadA = [&](int kt){
    #pragma unroll
    for (int i = 0; i < 2; ++i){
      int grow = mBase + arow[i];
      int col = kt*64 + acol8[i];
      if (grow < 10000 && col < 10000){
        float4 x = *(const float4*)(g + (long long)grow*10000 + col);
        float4 y = *(const float4*)(g + (long long)grow*10000 + col + 4);
        fA[i][0]=x.x; fA[i][1]=x.y; fA[i][2]=x.z; fA[i][3]=x.w;
        fA[i][4]=y.x; fA[i][5]=y.y; fA[i][6]=y.z; fA[i][7]=y.w;
      } else {
        #pragma unroll
        for (int j = 0; j < 8; ++j) fA[i][j] = 0.f;
      }
    }
  };
  auto writeA = [&](int buf, int kt){
    #pragma unroll
    for (int i = 0; i < 2; ++i){
      int ch = tid + 256*i;
      short8 v = pack8(fA[i]);
      *(short8*)(&sm[buf][ch*8]) = v;
      *(short8*)(g16 + (long long)(mBase + arow[i])*LDA + kt*64 + acol8[i]) = v;
    }
  };
  auto stageB = [&](int buf, int kt){
    unsigned short* dst = &sm[buf][64*64];
    const unsigned short* Bk = zT + (long long)kt*64;
    #pragma unroll
    for (int i = 0; i < 4; ++i){
      int c = i*256 + tid; int row = c >> 3, gr = c & 7;
      gl_lds16(Bk + (long long)row*LDA + ((gr ^ (row & 7))*8), dst + c*8);
    }
  };

  f32x4 acc[2][4];
  #pragma unroll
  for (int i = 0; i < 2; ++i)
    #pragma unroll
    for (int j = 0; j < 4; ++j){ f32x4 zz = {0.f,0.f,0.f,0.f}; acc[i][j] = zz; }

  loadA(kt0); stageB(0, kt0); writeA(0, kt0);
  int cur = 0;
  for (int kt = kt0; kt < kt1; ++kt){
    __syncthreads();
    const bool pf = (kt + 1 < kt1);
    if (pf){ loadA(kt+1); stageB(cur^1, kt+1); }
    const unsigned short* sp = &sm[cur][0];
    #pragma unroll
    for (int ks = 0; ks < 2; ++ks){
      short8 a[2], b[4];
      #pragma unroll
      for (int i = 0; i < 2; ++i){
        int row = wm*32 + i*16 + lr;
        a[i] = *(const short8*)(sp + row*64 + (((4*ks+lk) ^ (row & 7))*8));
      }
      #pragma unroll
      for (int j = 0; j < 4; ++j){
        int rb = wn*64 + j*16 + lr;
        b[j] = *(const short8*)(sp + 64*64 + rb*64 + (((4*ks+lk) ^ (rb & 7))*8));
      }
      #pragma unroll
      for (int i = 0; i < 2; ++i)
        #pragma unroll
        for (int j = 0; j < 4; ++j)
          acc[i][j] = MFMA16(a[i], b[j], acc[i][j]);
    }
    if (pf) writeA(cur^1, kt+1);
    cur ^= 1;
  }

  unsigned short* Pp = P + (long long)s*MROWS*ldp;
  #pragma unroll
  for (int i = 0; i < 2; ++i){
    const int row0 = mBase + wm*32 + i*16 + lk*4;
    #pragma unroll
    for (int j = 0; j < 4; ++j){
      const int col = wn*64 + j*16 + lr;
      #pragma unroll
      for (int r = 0; r < 4; ++r)
        Pp[(long long)(row0+r)*ldp + col] = f2bf(acc[i][j][r]);
    }
  }
}

// ================= 256x256 GEMM, split-K, bf16 partials =====================
// (r5-verified body; only the P store dtype changed)
__global__ __launch_bounds__(512)
void k_gemm8(const unsigned short* __restrict__ A,
             const unsigned short* __restrict__ B,
             unsigned short* __restrict__ P, int S, int ldp)
{
  __shared__ unsigned short sm[2][32768];

  const int tid = threadIdx.x;
  const int wid = tid >> 6, l = tid & 63;
  const int wm = wid >> 2, wn = wid & 3;
  const int lr = l & 15, lk = l >> 4;
  const int mBase = blockIdx.x * 256;
  const int nBase = blockIdx.y * 256;
  const int s = blockIdx.z;
  const int kt0 = (157*s)/S, kt1 = (157*(s+1))/S;

  const unsigned short* gsrc[8];
  int ldst[8];
  #pragma unroll
  for (int h = 0; h < 4; ++h){
    const unsigned short* base = (h < 2) ? A : B;
    const int rowBase = ((h < 2) ? mBase : nBase) + (h & 1) * 128;
    const int ldsOff = ((h < 2) ? 0 : 16384) + (h & 1) * 8192;
    #pragma unroll
    for (int i = 0; i < 2; ++i){
      int ch = tid + 512*i;
      int row = ch >> 3, gc = (ch & 7) ^ (row & 7);
      gsrc[h*2+i] = base + (long long)(rowBase + row)*LDA + gc*8;
      ldst[h*2+i] = ldsOff + ch*8;
    }
  }
  auto stage_tile = [&](unsigned short* dst, int kt){
    const long long ko = (long long)kt * 64;
    #pragma unroll
    for (int i = 0; i < 8; ++i)
      gl_lds16(gsrc[i] + ko, dst + ldst[i]);
  };

  f32x4 acc[8][4];
  #pragma unroll
  for (int i = 0; i < 8; ++i)
    #pragma unroll
    for (int j = 0; j < 4; ++j){ f32x4 zz = {0.f,0.f,0.f,0.f}; acc[i][j] = zz; }

  stage_tile(&sm[0][0], kt0);

  int cur = 0;
  for (int kt = kt0; kt < kt1; ++kt){
    const bool pf = (kt + 1 < kt1);
    unsigned short* nb = &sm[cur ^ 1][0];
    const unsigned short* sp = &sm[cur][0];

    if (pf){
      stage_tile(nb, kt + 1);
      __builtin_amdgcn_sched_barrier(0);
      asm volatile("s_waitcnt vmcnt(8)" ::: "memory");
    } else {
      asm volatile("s_waitcnt vmcnt(0)" ::: "memory");
    }
    __builtin_amdgcn_sched_barrier(0);
    __builtin_amdgcn_s_barrier();
    __builtin_amdgcn_sched_barrier(0);

    short8 bfr[4][2];
    #pragma unroll
    for (int jj = 0; jj < 4; ++jj){
      const int row = wn*64 + jj*16 + lr;
      #pragma unroll
      for (int ks = 0; ks < 2; ++ks)
        bfr[jj][ks] = *(const short8*)(sp + 16384 + row*64 + (((ks*4+lk) ^ (row & 7))*8));
    }
    #pragma unroll
    for (int ih = 0; ih < 2; ++ih){
      short8 af[4][2];
      #pragma unroll
      for (int ii = 0; ii < 4; ++ii){
        const int row = wm*128 + ih*64 + ii*16 + lr;
        #pragma unroll
        for (int ks = 0; ks < 2; ++ks)
          af[ii][ks] = *(const short8*)(sp + row*64 + (((ks*4+lk) ^ (row & 7))*8));
      }
      __builtin_amdgcn_s_setprio(1);
      #pragma unroll
      for (int ks = 0; ks < 2; ++ks)
        #pragma unroll
        for (int ii = 0; ii < 4; ++ii)
          #pragma unroll
          for (int jj = 0; jj < 4; ++jj)
            acc[ih*4+ii][jj] = MFMA16(af[ii][ks], bfr[jj][ks], acc[ih*4+ii][jj]);
      __builtin_amdgcn_s_setprio(0);
    }
    __builtin_amdgcn_sched_barrier(0);
    __builtin_amdgcn_s_barrier();
    __builtin_amdgcn_sched_barrier(0);
    cur ^= 1;
  }

  unsigned short* Pp = P + (long long)s*MROWS*ldp;
  #pragma unroll
  for (int i = 0; i < 8; ++i){
    const int row0 = mBase + wm*128 + i*16 + lk*4;
    #pragma unroll
    for (int j = 0; j < 4; ++j){
      const int col = nBase + wn*64 + j*16 + lr;
      #pragma unroll
      for (int r = 0; r < 4; ++r)
        Pp[(long long)(row0+r)*ldp + col] = f2bf(acc[i][j][r]);
    }
  }
}

// ---- fused small GEMM over summed bf16 partials ----
// A_eff[row][k] = sum_s P[s][row][k]; out = act(A_eff @ W^T)
// MODE 0: relu -> o1 = outT bf16 [NW][10048]
// MODE 1: relu -> o1 = z_T; rownorm -> o2 = znT; o3 = zn row-major [10000][256]
// MODE 2: sigmoid -> of f32 row-major [10000][NW]
template<int NW, int KW, int LDP, int S, int MODE>
__global__ __launch_bounds__(320)
void k_small(const unsigned short* __restrict__ P,
             const unsigned short* __restrict__ W,
             unsigned short* __restrict__ o1,
             unsigned short* __restrict__ o2,
             unsigned short* __restrict__ o3,
             float* __restrict__ of)
{
  const int tid = threadIdx.x, w = tid >> 6, l = tid & 63;
  const int lr = l & 15, lk = l >> 4;
  const int mBase = blockIdx.x * 80;
  constexpr int NF = NW/16;
  constexpr long long SSTR = MROWS*(long long)LDP;

  f32x4 acc[NF];
  #pragma unroll
  for (int f = 0; f < NF; ++f){ f32x4 zz = {0.f,0.f,0.f,0.f}; acc[f] = zz; }

  const unsigned short* ap = P + (long long)(mBase + 16*w + lr)*LDP + lk*8;
  #pragma unroll
  for (int kc = 0; kc < KW/32; ++kc){
    float av[8];
    short8 v0 = *(const short8*)(ap + kc*32);
    #pragma unroll
    for (int e = 0; e < 8; ++e) av[e] = bf2f((unsigned short)v0[e]);
    #pragma unroll
    for (int s2 = 1; s2 < S; ++s2){
      short8 v = *(const short8*)(ap + (long long)s2*SSTR + kc*32);
      #pragma unroll
      for (int e = 0; e < 8; ++e) av[e] += bf2f((unsigned short)v[e]);
    }
    short8 a = pack8(av);
    #pragma unroll
    for (int f = 0; f < NF; ++f){
      short8 b = *(const short8*)(W + (long long)(16*f+lr)*KW + kc*32 + lk*8);
      acc[f] = MFMA16(a, b, acc[f]);
    }
  }

  const int row0 = mBase + 16*w + lk*4;
  if constexpr (MODE == 2){
    #pragma unroll
    for (int f = 0; f < NF; ++f){
      const int col = 16*f + lr;
      #pragma unroll
      for (int r = 0; r < 4; ++r)
        of[(long long)(row0+r)*NW + col] = 1.0f / (1.0f + expf(-acc[f][r]));
    }
  } else if constexpr (MODE == 0){
    #pragma unroll
    for (int f = 0; f < NF; ++f){
      us4 v;
      #pragma unroll
      for (int r = 0; r < 4; ++r) v[r] = f2bf(fmaxf(acc[f][r], 0.0f));
      *(us4*)(o1 + (long long)(16*f+lr)*LDA + row0) = v;
    }
  } else {
    float ss[4] = {0.f,0.f,0.f,0.f};
    #pragma unroll
    for (int f = 0; f < NF; ++f)
      #pragma unroll
      for (int r = 0; r < 4; ++r){
        float v = fmaxf(acc[f][r], 0.0f);
        acc[f][r] = v;
        ss[r] += v*v;
      }
    #pragma unroll
    for (int r = 0; r < 4; ++r){
      #pragma unroll
      for (int off = 1; off <= 8; off <<= 1)
        ss[r] += __shfl_xor(ss[r], off, 64);
      ss[r] = 1.0f / fmaxf(sqrtf(ss[r]), 1e-12f);
    }
    #pragma unroll
    for (int f = 0; f < NF; ++f){
      const int col = 16*f + lr;
      us4 vz, vn;
      #pragma unroll
      for (int r = 0; r < 4; ++r){
        vz[r] = f2bf(acc[f][r]);
        vn[r] = f2bf(acc[f][r]*ss[r]);
        o3[(long long)(row0+r)*256 + col] = vn[r];
      }
      *(us4*)(o1 + (long long)col*LDA + row0) = vz;
      *(us4*)(o2 + (long long)col*LDA + row0) = vn;
    }
  }
}

// ---- fused reduce(bf16 partials) + APPNP epilogue + TRANSPOSED write ----
__global__ void k_reduce_T(const unsigned short* __restrict__ P, int S, int ldp, int colOff,
                           unsigned short* __restrict__ outT,
                           const unsigned short* __restrict__ H)
{
  __shared__ unsigned short t[64][65];
  const int rb = blockIdx.x*64, cb = blockIdx.y*64;
  const long long stride = MROWS * (long long)ldp;
  #pragma unroll
  for (int it = 0; it < 4; ++it){
    int idx = it*256 + threadIdx.x;
    int r = idx >> 4, c4 = (idx & 15)*4;
    int row = rb + r;
    float sv[4] = {0.f,0.f,0.f,0.f};
    if (row < 10000){
      const unsigned short* p = P + (long long)row*ldp + colOff + cb + c4;
      for (int s2 = 0; s2 < S; ++s2){
        us4 tt = *(const us4*)(p + (long long)s2*stride);
        sv[0] += bf2f(tt.x); sv[1] += bf2f(tt.y);
        sv[2] += bf2f(tt.z); sv[3] += bf2f(tt.w);
      }
      us4 h = *(const us4*)(H + (long long)row*256 + cb + c4);
      sv[0] = 0.5f*sv[0] + 0.5f*bf2f(h.x);
      sv[1] = 0.5f*sv[1] + 0.5f*bf2f(h.y);
      sv[2] = 0.5f*sv[2] + 0.5f*bf2f(h.z);
      sv[3] = 0.5f*sv[3] + 0.5f*bf2f(h.w);
    }
    t[c4+0][r] = f2bf(sv[0]); t[c4+1][r] = f2bf(sv[1]);
    t[c4+2][r] = f2bf(sv[2]); t[c4+3][r] = f2bf(sv[3]);
  }
  __syncthreads();
  #pragma unroll
  for (int it = 0; it < 4; ++it){
    int idx = it*256 + threadIdx.x;
    int ro = idx >> 4, co4 = (idx & 15)*4;
    us4 v; v.x=t[ro][co4]; v.y=t[ro][co4+1]; v.z=t[ro][co4+2]; v.w=t[ro][co4+3];
    *(us4*)(outT + (long long)(cb+ro)*LDA + rb + co4) = v;
  }
}

// ---- final reduce: Z3 = 0.5*sum + 0.5*zn -> f32 out ----
__global__ void k_reduce2(const unsigned short* __restrict__ P, int S, int ldp,
                          float* __restrict__ out, const unsigned short* __restrict__ H)
{
  const long long stride = MROWS * (long long)ldp;
  const int idx = blockIdx.x*256 + threadIdx.x;
  const int row = idx >> 6;
  const int c4 = (idx & 63)*4;
  const unsigned short* p = P + (long long)row*ldp + c4;
  float sv[4] = {0.f,0.f,0.f,0.f};
  for (int s2 = 0; s2 < S; ++s2){
    us4 tt = *(const us4*)(p + (long long)s2*stride);
    sv[0] += bf2f(tt.x); sv[1] += bf2f(tt.y);
    sv[2] += bf2f(tt.z); sv[3] += bf2f(tt.w);
  }
  us4 h = *(const us4*)(H + (long long)row*256 + c4);
  float4 o;
  o.x = 0.5f*sv[0] + 0.5f*bf2f(h.x);
  o.y = 0.5f*sv[1] + 0.5f*bf2f(h.y);
  o.z = 0.5f*sv[2] + 0.5f*bf2f(h.z);
  o.w = 0.5f*sv[3] + 0.5f*bf2f(h.w);
  *(float4*)(out + (long long)row*256 + c4) = o;
}

extern "C" void kernel_launch(void* const* d_in, const int* in_sizes, int n_in,
                              void* d_out, int out_size, void* d_ws, size_t ws_size,
                              hipStream_t stream)
{
  const float* g   = (const float*)d_in[0];
  const float* z   = (const float*)d_in[1];
  const float* W1  = (const float*)d_in[2];
  const float* W1_ = (const float*)d_in[3];
  const float* W2  = (const float*)d_in[4];

  char* ws = (char*)d_ws;
  size_t off = 0;
  auto alloc = [&](size_t bytes)->void*{
    void* p = ws + off; off += (bytes + 255) & ~(size_t)255; return p;
  };
  unsigned short* g16  = (unsigned short*)alloc(10240ULL*10048*2); // 206 MB
  unsigned short* zT   = (unsigned short*)alloc(128ULL*10048*2);
  unsigned short* W1c  = (unsigned short*)alloc(256ULL*128*2);
  unsigned short* W1_c = (unsigned short*)alloc(256ULL*256*2);
  unsigned short* W2c  = (unsigned short*)alloc(128ULL*256*2);
  unsigned short* Tbuf = (unsigned short*)alloc(512ULL*10048*2);   // transposed operands
  unsigned short* zn   = (unsigned short*)alloc(10000ULL*256*2);
  unsigned short* P    = (unsigned short*)alloc(10240ULL*1536*2);  // 31.5 MB bf16 partials
  (void)ws_size; (void)in_sizes; (void)n_in; (void)out_size;

  float* res  = (float*)d_out;                    // [10000][128]
  float* Zout = (float*)d_out + 10000LL*128;      // [10000][256]
  unsigned short* znT = Tbuf + 256LL*10048;

  // init / conversions
  k_zero<<<dim3(512), dim3(256), 0, stream>>>(g16, Tbuf);
  k_tconv_z<<<dim3(157,2), dim3(256), 0, stream>>>(z, zT);
  k_conv_w<<<dim3(120), dim3(256), 0, stream>>>(W1, W1c, 256*128/4,
                                                W1_, W1_c, 256*256/4,
                                                W2, W2c, 128*256/4);

  // t0 = g @ z (fused f32->bf16 conversion of g; writes g16 + bf16 partials)
  k_gemm_t0<<<dim3(157,1,3), dim3(256), 0, stream>>>(g, zT, g16, P, 3);
  // z1^T = T(relu(t0 @ W1^T))   [fused partial-sum + transpose]
  k_small<256,128,128,3,0><<<dim3(125), dim3(320), 0, stream>>>(P, W1c, Tbuf, nullptr, nullptr, nullptr);
  // t1 = g @ z1 (N=256, S=6)
  k_gemm8<<<dim3(40,1,6), dim3(512), 0, stream>>>(g16, Tbuf, P, 6, 256);
  // z_^T, zn^T, zn  [fused partial-sum + relu + rownorm + transposes]
  k_small<256,256,256,6,1><<<dim3(125), dim3(320), 0, stream>>>(P, W1_c, Tbuf, znT, zn, nullptr);
  // [t2 | g@zn] = g @ [z_ | zn]  (N=512, S=3)
  k_gemm8<<<dim3(40,2,3), dim3(512), 0, stream>>>(g16, Tbuf, P, 3, 512);
  // res = sigmoid(t2 @ W2^T)  [fused partial-sum]
  k_small<128,256,512,3,2><<<dim3(125), dim3(320), 0, stream>>>(P, W2c, nullptr, nullptr, nullptr, res);
  // Z1^T = T(0.5*(g@zn) + 0.5*zn)
  k_reduce_T<<<dim3(157,4), dim3(256), 0, stream>>>(P, 3, 512, 256, Tbuf, zn);
  // Z2^T = T(0.5*(g@Z1) + 0.5*zn)
  k_gemm8<<<dim3(40,1,6), dim3(512), 0, stream>>>(g16, Tbuf, P, 6, 256);
  k_reduce_T<<<dim3(157,4), dim3(256), 0, stream>>>(P, 6, 256, 0, Tbuf, zn);
  // Z3 = 0.5*(g@Z2) + 0.5*zn -> f32 d_out
  k_gemm8<<<dim3(40,1,6), dim3(512), 0, stream>>>(g16, Tbuf, P, 6, 256);
  k_reduce2<<<dim3(2500), dim3(256), 0, stream>>>(P, 6, 256, Zout, zn);
}

// Round 7
// 550.956 us; speedup vs baseline: 1.2111x; 1.0140x over previous
//
#include <hip/hip_runtime.h>
#include <stdint.h>

typedef __attribute__((ext_vector_type(8))) short short8;
typedef __attribute__((ext_vector_type(4))) float f32x4;
typedef __attribute__((ext_vector_type(4))) unsigned short us4;

#define MFMA16(a,b,c) __builtin_amdgcn_mfma_f32_16x16x32_bf16((a),(b),(c),0,0,0)

static __device__ __forceinline__ float bf2f(unsigned short u){
  union { float f; unsigned int i; } c; c.i = ((unsigned int)u) << 16; return c.f;
}
static __device__ __forceinline__ unsigned short f2bf(float f){
  union { float f; unsigned int i; } c; c.f = f;
  unsigned int x = c.i;
  unsigned int r = x + 0x7fffu + ((x >> 16) & 1u);
  return (unsigned short)(r >> 16);
}
static __device__ __forceinline__ short8 pack8(const float* v){
  short8 r;
  #pragma unroll
  for (int i = 0; i < 8; ++i) r[i] = (short)f2bf(v[i]);
  return r;
}

typedef const __attribute__((address_space(1))) void cg_void;
typedef __attribute__((address_space(3))) void lds_void;
static __device__ __forceinline__ void gl_lds16(const void* g, void* l){
  __builtin_amdgcn_global_load_lds((cg_void*)g, (lds_void*)l, 16, 0, 0);
}

#define MROWS 10240LL
#define LDA   10048

// ---- zero-pad Tbuf cols 10000..10047 for rows 0..511 ----
__global__ void k_zero(unsigned short* __restrict__ Tbuf){
  short8 z = {0,0,0,0,0,0,0,0};
  for (int c = blockIdx.x*256 + threadIdx.x; c < 512*6; c += gridDim.x*256){
    int row = c/6, k = c%6;
    *(short8*)(Tbuf + (long long)row*LDA + 10000 + k*8) = z;
  }
}

// ---- convert the 3 weight matrices in one launch ----
__global__ void k_conv_w(const float* __restrict__ a, unsigned short* __restrict__ oa, int na4,
                         const float* __restrict__ b, unsigned short* __restrict__ ob, int nb4,
                         const float* __restrict__ c, unsigned short* __restrict__ oc, int nc4){
  for (int i = blockIdx.x*blockDim.x + threadIdx.x; i < na4 + nb4 + nc4;
       i += gridDim.x*blockDim.x){
    const float* src; unsigned short* dst; int j = i;
    if (j < na4){ src = a; dst = oa; }
    else if (j < na4 + nb4){ j -= na4; src = b; dst = ob; }
    else { j -= na4 + nb4; src = c; dst = oc; }
    float4 f = *(const float4*)(src + (long long)j*4);
    us4 v; v.x=f2bf(f.x); v.y=f2bf(f.y); v.z=f2bf(f.z); v.w=f2bf(f.w);
    *(us4*)(dst + (long long)j*4) = v;
  }
}

// ---- transpose-convert z: f32 [10000][128] -> bf16 [128][10048] ----
__global__ void k_tconv_z(const float* __restrict__ z, unsigned short* __restrict__ o){
  __shared__ unsigned short t[64][65];
  const int rb = blockIdx.x*64, cb = blockIdx.y*64;
  #pragma unroll
  for (int it = 0; it < 4; ++it){
    int idx = it*256 + threadIdx.x;
    int r = idx >> 4, c4 = (idx & 15) * 4;
    float4 f = {0.f,0.f,0.f,0.f};
    if (rb + r < 10000) f = *(const float4*)(z + (long long)(rb+r)*128 + cb + c4);
    t[c4+0][r] = f2bf(f.x); t[c4+1][r] = f2bf(f.y);
    t[c4+2][r] = f2bf(f.z); t[c4+3][r] = f2bf(f.w);
  }
  __syncthreads();
  #pragma unroll
  for (int it = 0; it < 4; ++it){
    int idx = it*256 + threadIdx.x;
    int ro = idx >> 4, co4 = (idx & 15) * 4;
    us4 v; v.x=t[ro][co4]; v.y=t[ro][co4+1]; v.z=t[ro][co4+2]; v.w=t[ro][co4+3];
    *(us4*)(o + (long long)(cb+ro)*LDA + rb + co4) = v;
  }
}

// ======= fused t0: BM=256, BN=128, 8 waves (4M x 2N, wave 64x64) =======
// Reads f32 g (reg-staged, converts), writes g16 (all 10240 rows, zeros in
// pad region) + bf16 t0 partials. B (zT) via gl_lds. LDS (32+16)KB x2 = 96 KB.
__global__ __launch_bounds__(512)
void k_gemm_t0(const float* __restrict__ g, const unsigned short* __restrict__ zT,
               unsigned short* __restrict__ g16, unsigned short* __restrict__ P, int S)
{
  constexpr int ldp = 128;
  __shared__ unsigned short sm[2][24576];   // A 16384 + B 8192 shorts

  const int tid = threadIdx.x;
  const int wid = tid >> 6, l = tid & 63;
  const int wm = wid >> 1, wn = wid & 1;
  const int lr = l & 15, lk = l >> 4;
  const int mBase = blockIdx.x * 256;
  const int s = blockIdx.z;
  const int kt0 = (157*s)/S, kt1 = (157*(s+1))/S;

  int arow[4], acol8[4];
  #pragma unroll
  for (int i = 0; i < 4; ++i){
    int ch = tid + 512*i;
    int row = ch >> 3, gr = ch & 7;
    arow[i] = row; acol8[i] = ((gr ^ (row & 7)) * 8);
  }
  float fA[4][8];
  auto loadA = [&](int kt){
    #pragma unroll
    for (int i = 0; i < 4; ++i){
      int grow = mBase + arow[i];
      int col = kt*64 + acol8[i];
      if (grow < 10000 && col < 10000){
        float4 x = *(const float4*)(g + (long long)grow*10000 + col);
        float4 y = *(const float4*)(g + (long long)grow*10000 + col + 4);
        fA[i][0]=x.x; fA[i][1]=x.y; fA[i][2]=x.z; fA[i][3]=x.w;
        fA[i][4]=y.x; fA[i][5]=y.y; fA[i][6]=y.z; fA[i][7]=y.w;
      } else {
        #pragma unroll
        for (int j = 0; j < 8; ++j) fA[i][j] = 0.f;
      }
    }
  };
  auto writeA = [&](int buf, int kt){
    #pragma unroll
    for (int i = 0; i < 4; ++i){
      int ch = tid + 512*i;
      short8 v = pack8(fA[i]);
      *(short8*)(&sm[buf][ch*8]) = v;
      *(short8*)(g16 + (long long)(mBase + arow[i])*LDA + kt*64 + acol8[i]) = v;
    }
  };
  auto stageB = [&](int buf, int kt){
    unsigned short* dst = &sm[buf][16384];
    const unsigned short* Bk = zT + (long long)kt*64;
    #pragma unroll
    for (int i = 0; i < 2; ++i){
      int c = i*512 + tid; int row = c >> 3, gr = c & 7;
      gl_lds16(Bk + (long long)row*LDA + ((gr ^ (row & 7))*8), dst + c*8);
    }
  };

  f32x4 acc[4][4];
  #pragma unroll
  for (int i = 0; i < 4; ++i)
    #pragma unroll
    for (int j = 0; j < 4; ++j){ f32x4 zz = {0.f,0.f,0.f,0.f}; acc[i][j] = zz; }

  loadA(kt0); stageB(0, kt0); writeA(0, kt0);
  int cur = 0;
  for (int kt = kt0; kt < kt1; ++kt){
    __syncthreads();
    const bool pf = (kt + 1 < kt1);
    if (pf){ loadA(kt+1); stageB(cur^1, kt+1); }
    const unsigned short* sp = &sm[cur][0];
    #pragma unroll
    for (int ks = 0; ks < 2; ++ks){
      short8 a[4];
      #pragma unroll
      for (int i = 0; i < 4; ++i){
        int row = wm*64 + i*16 + lr;
        a[i] = *(const short8*)(sp + row*64 + (((4*ks+lk) ^ (row & 7))*8));
      }
      #pragma unroll
      for (int j = 0; j < 4; ++j){
        int rb = wn*64 + j*16 + lr;
        short8 b = *(const short8*)(sp + 16384 + rb*64 + (((4*ks+lk) ^ (rb & 7))*8));
        #pragma unroll
        for (int i = 0; i < 4; ++i)
          acc[i][j] = MFMA16(a[i], b, acc[i][j]);
      }
    }
    if (pf) writeA(cur^1, kt+1);
    cur ^= 1;
  }

  unsigned short* Pp = P + (long long)s*MROWS*ldp;
  #pragma unroll
  for (int i = 0; i < 4; ++i){
    const int row0 = mBase + wm*64 + i*16 + lk*4;
    #pragma unroll
    for (int j = 0; j < 4; ++j){
      const int col = wn*64 + j*16 + lr;
      #pragma unroll
      for (int r = 0; r < 4; ++r)
        Pp[(long long)(row0+r)*ldp + col] = f2bf(acc[i][j][r]);
    }
  }
}

// ======= 256xBN GEMM, split-K, bf16 partials (r5/r6-verified body) =======
template<int BN>
__global__ __launch_bounds__(512)
void k_gemm8(const unsigned short* __restrict__ A,
             const unsigned short* __restrict__ B,
             unsigned short* __restrict__ P, int S, int ldp, int nBase)
{
  constexpr int WNS = BN/4;
  constexpr int NJ  = WNS/16;
  constexpr int BCH = BN/64;
  constexpr int NLD = 4 + BCH;
  __shared__ unsigned short sm[2][16384 + BN*64];

  const int tid = threadIdx.x;
  const int wid = tid >> 6, l = tid & 63;
  const int wm = wid >> 2, wn = wid & 3;
  const int lr = l & 15, lk = l >> 4;
  const int mBase = blockIdx.x * 256;
  const int s = blockIdx.z;
  const int kt0 = (157*s)/S, kt1 = (157*(s+1))/S;

  const unsigned short* gsrc[NLD];
  int ldst[NLD];
  #pragma unroll
  for (int i = 0; i < 4; ++i){
    int ch = tid + 512*i;
    int row = ch >> 3, gc = (ch & 7) ^ (row & 7);
    gsrc[i] = A + (long long)(mBase + row)*LDA + gc*8;
    ldst[i] = ch*8;
  }
  #pragma unroll
  for (int i = 0; i < BCH; ++i){
    int ch = tid + 512*i;
    int row = ch >> 3, gc = (ch & 7) ^ (row & 7);
    gsrc[4+i] = B + (long long)(nBase + row)*LDA + gc*8;
    ldst[4+i] = 16384 + ch*8;
  }
  auto stage_tile = [&](unsigned short* dst, int kt){
    const long long ko = (long long)kt * 64;
    #pragma unroll
    for (int i = 0; i < NLD; ++i)
      gl_lds16(gsrc[i] + ko, dst + ldst[i]);
  };

  f32x4 acc[8][NJ];
  #pragma unroll
  for (int i = 0; i < 8; ++i)
    #pragma unroll
    for (int j = 0; j < NJ; ++j){ f32x4 zz = {0.f,0.f,0.f,0.f}; acc[i][j] = zz; }

  stage_tile(&sm[0][0], kt0);

  int cur = 0;
  for (int kt = kt0; kt < kt1; ++kt){
    const bool pf = (kt + 1 < kt1);
    unsigned short* nb = &sm[cur ^ 1][0];
    const unsigned short* sp = &sm[cur][0];

    if (pf){
      stage_tile(nb, kt + 1);
      __builtin_amdgcn_sched_barrier(0);
      if constexpr (BN == 256) asm volatile("s_waitcnt vmcnt(8)" ::: "memory");
      else                     asm volatile("s_waitcnt vmcnt(6)" ::: "memory");
    } else {
      asm volatile("s_waitcnt vmcnt(0)" ::: "memory");
    }
    __builtin_amdgcn_sched_barrier(0);
    __builtin_amdgcn_s_barrier();
    __builtin_amdgcn_sched_barrier(0);

    short8 bfr[NJ][2];
    #pragma unroll
    for (int jj = 0; jj < NJ; ++jj){
      const int row = wn*WNS + jj*16 + lr;
      #pragma unroll
      for (int ks = 0; ks < 2; ++ks)
        bfr[jj][ks] = *(const short8*)(sp + 16384 + row*64 + (((ks*4+lk) ^ (row & 7))*8));
    }
    #pragma unroll
    for (int ih = 0; ih < 2; ++ih){
      short8 af[4][2];
      #pragma unroll
      for (int ii = 0; ii < 4; ++ii){
        const int row = wm*128 + ih*64 + ii*16 + lr;
        #pragma unroll
        for (int ks = 0; ks < 2; ++ks)
          af[ii][ks] = *(const short8*)(sp + row*64 + (((ks*4+lk) ^ (row & 7))*8));
      }
      __builtin_amdgcn_s_setprio(1);
      #pragma unroll
      for (int ks = 0; ks < 2; ++ks)
        #pragma unroll
        for (int ii = 0; ii < 4; ++ii)
          #pragma unroll
          for (int jj = 0; jj < NJ; ++jj)
            acc[ih*4+ii][jj] = MFMA16(af[ii][ks], bfr[jj][ks], acc[ih*4+ii][jj]);
      __builtin_amdgcn_s_setprio(0);
    }
    __builtin_amdgcn_sched_barrier(0);
    __builtin_amdgcn_s_barrier();
    __builtin_amdgcn_sched_barrier(0);
    cur ^= 1;
  }

  unsigned short* Pp = P + (long long)s*MROWS*ldp;
  #pragma unroll
  for (int i = 0; i < 8; ++i){
    const int row0 = mBase + wm*128 + i*16 + lk*4;
    #pragma unroll
    for (int j = 0; j < NJ; ++j){
      const int col = nBase + wn*WNS + j*16 + lr;
      #pragma unroll
      for (int r = 0; r < 4; ++r)
        Pp[(long long)(row0+r)*ldp + col] = f2bf(acc[i][j][r]);
    }
  }
}

// ---- fused small GEMM over summed bf16 partials ----
// MODE 0: (optional relu) -> o1 = outT bf16 [NW][10048]
// MODE 1: relu -> o3 = z_ row [10000][256]; rownorm -> o1 = znT, o2 = zn row
template<int NW, int KW, int LDP, int S, int MODE>
__global__ __launch_bounds__(320)
void k_small(const unsigned short* __restrict__ P,
             const unsigned short* __restrict__ W,
             unsigned short* __restrict__ o1,
             unsigned short* __restrict__ o2,
             unsigned short* __restrict__ o3,
             int doRelu)
{
  const int tid = threadIdx.x, w = tid >> 6, l = tid & 63;
  const int lr = l & 15, lk = l >> 4;
  const int mBase = blockIdx.x * 80;
  constexpr int NF = NW/16;
  constexpr long long SSTR = MROWS*(long long)LDP;

  f32x4 acc[NF];
  #pragma unroll
  for (int f = 0; f < NF; ++f){ f32x4 zz = {0.f,0.f,0.f,0.f}; acc[f] = zz; }

  const unsigned short* ap = P + (long long)(mBase + 16*w + lr)*LDP + lk*8;
  #pragma unroll
  for (int kc = 0; kc < KW/32; ++kc){
    float av[8];
    short8 v0 = *(const short8*)(ap + kc*32);
    #pragma unroll
    for (int e = 0; e < 8; ++e) av[e] = bf2f((unsigned short)v0[e]);
    #pragma unroll
    for (int s2 = 1; s2 < S; ++s2){
      short8 v = *(const short8*)(ap + (long long)s2*SSTR + kc*32);
      #pragma unroll
      for (int e = 0; e < 8; ++e) av[e] += bf2f((unsigned short)v[e]);
    }
    short8 a = pack8(av);
    #pragma unroll
    for (int f = 0; f < NF; ++f){
      short8 b = *(const short8*)(W + (long long)(16*f+lr)*KW + kc*32 + lk*8);
      acc[f] = MFMA16(a, b, acc[f]);
    }
  }

  const int row0 = mBase + 16*w + lk*4;
  if constexpr (MODE == 0){
    #pragma unroll
    for (int f = 0; f < NF; ++f){
      us4 v;
      #pragma unroll
      for (int r = 0; r < 4; ++r){
        float x = acc[f][r];
        if (doRelu) x = fmaxf(x, 0.0f);
        v[r] = f2bf(x);
      }
      *(us4*)(o1 + (long long)(16*f+lr)*LDA + row0) = v;
    }
  } else {
    float ss[4] = {0.f,0.f,0.f,0.f};
    #pragma unroll
    for (int f = 0; f < NF; ++f)
      #pragma unroll
      for (int r = 0; r < 4; ++r){
        float v = fmaxf(acc[f][r], 0.0f);
        acc[f][r] = v;
        ss[r] += v*v;
      }
    #pragma unroll
    for (int r = 0; r < 4; ++r){
      #pragma unroll
      for (int off = 1; off <= 8; off <<= 1)
        ss[r] += __shfl_xor(ss[r], off, 64);
      ss[r] = 1.0f / fmaxf(sqrtf(ss[r]), 1e-12f);
    }
    #pragma unroll
    for (int f = 0; f < NF; ++f){
      const int col = 16*f + lr;
      us4 vn;
      #pragma unroll
      for (int r = 0; r < 4; ++r){
        float zr = acc[f][r];
        float nr = zr * ss[r];
        vn[r] = f2bf(nr);
        o2[(long long)(row0+r)*256 + col] = vn[r];     // zn row-major
        o3[(long long)(row0+r)*256 + col] = f2bf(zr);  // z_ row-major
      }
      *(us4*)(o1 + (long long)col*LDA + row0) = vn;    // znT
    }
  }
}

// ---- fused reduce(bf16 partials) + APPNP epilogue + TRANSPOSED write ----
__global__ void k_reduce_T(const unsigned short* __restrict__ P, int S, int ldp, int colOff,
                           unsigned short* __restrict__ outT,
                           const unsigned short* __restrict__ H)
{
  __shared__ unsigned short t[64][65];
  const int rb = blockIdx.x*64, cb = blockIdx.y*64;
  const long long stride = MROWS * (long long)ldp;
  #pragma unroll
  for (int it = 0; it < 4; ++it){
    int idx = it*256 + threadIdx.x;
    int r = idx >> 4, c4 = (idx & 15)*4;
    int row = rb + r;
    float sv[4] = {0.f,0.f,0.f,0.f};
    if (row < 10000){
      const unsigned short* p = P + (long long)row*ldp + colOff + cb + c4;
      for (int s2 = 0; s2 < S; ++s2){
        us4 tt = *(const us4*)(p + (long long)s2*stride);
        sv[0] += bf2f(tt.x); sv[1] += bf2f(tt.y);
        sv[2] += bf2f(tt.z); sv[3] += bf2f(tt.w);
      }
      us4 h = *(const us4*)(H + (long long)row*256 + cb + c4);
      sv[0] = 0.5f*sv[0] + 0.5f*bf2f(h.x);
      sv[1] = 0.5f*sv[1] + 0.5f*bf2f(h.y);
      sv[2] = 0.5f*sv[2] + 0.5f*bf2f(h.z);
      sv[3] = 0.5f*sv[3] + 0.5f*bf2f(h.w);
    }
    t[c4+0][r] = f2bf(sv[0]); t[c4+1][r] = f2bf(sv[1]);
    t[c4+2][r] = f2bf(sv[2]); t[c4+3][r] = f2bf(sv[3]);
  }
  __syncthreads();
  #pragma unroll
  for (int it = 0; it < 4; ++it){
    int idx = it*256 + threadIdx.x;
    int ro = idx >> 4, co4 = (idx & 15)*4;
    us4 v; v.x=t[ro][co4]; v.y=t[ro][co4+1]; v.z=t[ro][co4+2]; v.w=t[ro][co4+3];
    *(us4*)(outT + (long long)(cb+ro)*LDA + rb + co4) = v;
  }
}

// ---- reduce partials + sigmoid -> f32 res [10000][128] ----
__global__ void k_reduce_sig(const unsigned short* __restrict__ P, int S,
                             float* __restrict__ out)
{
  const long long stride = MROWS * 128LL;
  const int idx = blockIdx.x*256 + threadIdx.x;
  const int row = idx >> 5;
  const int c4 = (idx & 31)*4;
  const unsigned short* p = P + (long long)row*128 + c4;
  float sv[4] = {0.f,0.f,0.f,0.f};
  for (int s2 = 0; s2 < S; ++s2){
    us4 tt = *(const us4*)(p + (long long)s2*stride);
    sv[0] += bf2f(tt.x); sv[1] += bf2f(tt.y);
    sv[2] += bf2f(tt.z); sv[3] += bf2f(tt.w);
  }
  float4 o;
  o.x = 1.0f/(1.0f + expf(-sv[0]));
  o.y = 1.0f/(1.0f + expf(-sv[1]));
  o.z = 1.0f/(1.0f + expf(-sv[2]));
  o.w = 1.0f/(1.0f + expf(-sv[3]));
  *(float4*)(out + (long long)row*128 + c4) = o;
}

// ---- final reduce: Z3 = 0.5*sum + 0.5*zn -> f32 out ----
__global__ void k_reduce2(const unsigned short* __restrict__ P, int S, int ldp,
                          float* __restrict__ out, const unsigned short* __restrict__ H)
{
  const long long stride = MROWS * (long long)ldp;
  const int idx = blockIdx.x*256 + threadIdx.x;
  const int row = idx >> 6;
  const int c4 = (idx & 63)*4;
  const unsigned short* p = P + (long long)row*ldp + c4;
  float sv[4] = {0.f,0.f,0.f,0.f};
  for (int s2 = 0; s2 < S; ++s2){
    us4 tt = *(const us4*)(p + (long long)s2*stride);
    sv[0] += bf2f(tt.x); sv[1] += bf2f(tt.y);
    sv[2] += bf2f(tt.z); sv[3] += bf2f(tt.w);
  }
  us4 h = *(const us4*)(H + (long long)row*256 + c4);
  float4 o;
  o.x = 0.5f*sv[0] + 0.5f*bf2f(h.x);
  o.y = 0.5f*sv[1] + 0.5f*bf2f(h.y);
  o.z = 0.5f*sv[2] + 0.5f*bf2f(h.z);
  o.w = 0.5f*sv[3] + 0.5f*bf2f(h.w);
  *(float4*)(out + (long long)row*256 + c4) = o;
}

extern "C" void kernel_launch(void* const* d_in, const int* in_sizes, int n_in,
                              void* d_out, int out_size, void* d_ws, size_t ws_size,
                              hipStream_t stream)
{
  const float* g   = (const float*)d_in[0];
  const float* z   = (const float*)d_in[1];
  const float* W1  = (const float*)d_in[2];
  const float* W1_ = (const float*)d_in[3];
  const float* W2  = (const float*)d_in[4];

  char* ws = (char*)d_ws;
  size_t off = 0;
  auto alloc = [&](size_t bytes)->void*{
    void* p = ws + off; off += (bytes + 255) & ~(size_t)255; return p;
  };
  unsigned short* g16  = (unsigned short*)alloc(10240ULL*10048*2);
  unsigned short* zT   = (unsigned short*)alloc(128ULL*10048*2);
  unsigned short* W1c  = (unsigned short*)alloc(256ULL*128*2);
  unsigned short* W1_c = (unsigned short*)alloc(256ULL*256*2);
  unsigned short* W2c  = (unsigned short*)alloc(128ULL*256*2);
  unsigned short* Tbuf = (unsigned short*)alloc(512ULL*10048*2);
  unsigned short* zn   = (unsigned short*)alloc(10000ULL*256*2);
  unsigned short* Xbuf = (unsigned short*)alloc(10000ULL*256*2);
  unsigned short* P    = (unsigned short*)alloc(10240ULL*1536*2);
  (void)ws_size; (void)in_sizes; (void)n_in; (void)out_size;

  float* res  = (float*)d_out;
  float* Zout = (float*)d_out + 10000LL*128;
  unsigned short* y2T = Tbuf + 256LL*LDA;

  k_zero<<<dim3(12), dim3(256), 0, stream>>>(Tbuf);
  k_tconv_z<<<dim3(157,2), dim3(256), 0, stream>>>(z, zT);
  k_conv_w<<<dim3(120), dim3(256), 0, stream>>>(W1, W1c, 256*128/4,
                                                W1_, W1_c, 256*256/4,
                                                W2, W2c, 128*256/4);

  // t0 = g @ z (writes g16 + partials), S=6
  k_gemm_t0<<<dim3(40,1,6), dim3(512), 0, stream>>>(g, zT, g16, P, 6);
  // z1^T -> Tbuf rows 0..255
  k_small<256,128,128,6,0><<<dim3(125), dim3(320), 0, stream>>>(P, W1c, Tbuf, nullptr, nullptr, 1);
  // t1 = g @ z1
  k_gemm8<256><<<dim3(40,1,6), dim3(512), 0, stream>>>(g16, Tbuf, P, 6, 256, 0);
  // znT -> Tbuf, zn row, z_ row -> Xbuf
  k_small<256,256,256,6,1><<<dim3(125), dim3(320), 0, stream>>>(P, W1_c, Tbuf, zn, Xbuf, 0);
  // y2^T = T(z_ @ W2^T) -> Tbuf rows 256..383
  k_small<128,256,256,1,0><<<dim3(125), dim3(320), 0, stream>>>(Xbuf, W2c, y2T, nullptr, nullptr, 0);
  // u1 = g @ zn
  k_gemm8<256><<<dim3(40,1,6), dim3(512), 0, stream>>>(g16, Tbuf, P, 6, 256, 0);
  // Z1^T -> Tbuf rows 0..255
  k_reduce_T<<<dim3(157,4), dim3(256), 0, stream>>>(P, 6, 256, 0, Tbuf, zn);
  // r = g @ y2 (N=128)
  k_gemm8<128><<<dim3(40,1,6), dim3(512), 0, stream>>>(g16, y2T, P, 6, 128, 0);
  // res = sigmoid(r)
  k_reduce_sig<<<dim3(1250), dim3(256), 0, stream>>>(P, 6, res);
  // Z2
  k_gemm8<256><<<dim3(40,1,6), dim3(512), 0, stream>>>(g16, Tbuf, P, 6, 256, 0);
  k_reduce_T<<<dim3(157,4), dim3(256), 0, stream>>>(P, 6, 256, 0, Tbuf, zn);
  // Z3 -> f32 d_out
  k_gemm8<256><<<dim3(40,1,6), dim3(512), 0, stream>>>(g16, Tbuf, P, 6, 256, 0);
  k_reduce2<<<dim3(2500), dim3(256), 0, stream>>>(P, 6, 256, Zout, zn);
}

// Round 8
// 542.905 us; speedup vs baseline: 1.2290x; 1.0148x over previous
//
#include <hip/hip_runtime.h>
#include <stdint.h>

typedef __attribute__((ext_vector_type(8))) short short8;
typedef __attribute__((ext_vector_type(4))) float f32x4;
typedef __attribute__((ext_vector_type(4))) unsigned short us4;

#define MFMA16(a,b,c) __builtin_amdgcn_mfma_f32_16x16x32_bf16((a),(b),(c),0,0,0)

static __device__ __forceinline__ float bf2f(unsigned short u){
  union { float f; unsigned int i; } c; c.i = ((unsigned int)u) << 16; return c.f;
}
static __device__ __forceinline__ unsigned short f2bf(float f){
  union { float f; unsigned int i; } c; c.f = f;
  unsigned int x = c.i;
  unsigned int r = x + 0x7fffu + ((x >> 16) & 1u);
  return (unsigned short)(r >> 16);
}
static __device__ __forceinline__ short8 pack8(const float* v){
  short8 r;
  #pragma unroll
  for (int i = 0; i < 8; ++i) r[i] = (short)f2bf(v[i]);
  return r;
}

typedef const __attribute__((address_space(1))) void cg_void;
typedef __attribute__((address_space(3))) void lds_void;
static __device__ __forceinline__ void gl_lds16(const void* g, void* l){
  __builtin_amdgcn_global_load_lds((cg_void*)g, (lds_void*)l, 16, 0, 0);
}

#define MROWS 10240LL
#define LDA   10048
// g16 tiled layout: g16t[mtile][kt][16384 shorts], mtile<40, kt<157.
// Chunk ch (0..2047) of a tile holds global (row=mtile*256+(ch>>3),
// colblock=((ch&7)^(row&7))) -- identical content map to the old row-major
// staging, just relocated so each (block, K-tile) A-read is one linear 32 KB.
#define GTILE 16384LL

// ---- zero-pad Tbuf cols 10000..10047 for rows 0..511 ----
__global__ void k_zero(unsigned short* __restrict__ Tbuf){
  short8 z = {0,0,0,0,0,0,0,0};
  for (int c = blockIdx.x*256 + threadIdx.x; c < 512*6; c += gridDim.x*256){
    int row = c/6, k = c%6;
    *(short8*)(Tbuf + (long long)row*LDA + 10000 + k*8) = z;
  }
}

// ---- convert the 3 weight matrices in one launch ----
__global__ void k_conv_w(const float* __restrict__ a, unsigned short* __restrict__ oa, int na4,
                         const float* __restrict__ b, unsigned short* __restrict__ ob, int nb4,
                         const float* __restrict__ c, unsigned short* __restrict__ oc, int nc4){
  for (int i = blockIdx.x*blockDim.x + threadIdx.x; i < na4 + nb4 + nc4;
       i += gridDim.x*blockDim.x){
    const float* src; unsigned short* dst; int j = i;
    if (j < na4){ src = a; dst = oa; }
    else if (j < na4 + nb4){ j -= na4; src = b; dst = ob; }
    else { j -= na4 + nb4; src = c; dst = oc; }
    float4 f = *(const float4*)(src + (long long)j*4);
    us4 v; v.x=f2bf(f.x); v.y=f2bf(f.y); v.z=f2bf(f.z); v.w=f2bf(f.w);
    *(us4*)(dst + (long long)j*4) = v;
  }
}

// ---- transpose-convert z: f32 [10000][128] -> bf16 [128][10048] ----
__global__ void k_tconv_z(const float* __restrict__ z, unsigned short* __restrict__ o){
  __shared__ unsigned short t[64][65];
  const int rb = blockIdx.x*64, cb = blockIdx.y*64;
  #pragma unroll
  for (int it = 0; it < 4; ++it){
    int idx = it*256 + threadIdx.x;
    int r = idx >> 4, c4 = (idx & 15) * 4;
    float4 f = {0.f,0.f,0.f,0.f};
    if (rb + r < 10000) f = *(const float4*)(z + (long long)(rb+r)*128 + cb + c4);
    t[c4+0][r] = f2bf(f.x); t[c4+1][r] = f2bf(f.y);
    t[c4+2][r] = f2bf(f.z); t[c4+3][r] = f2bf(f.w);
  }
  __syncthreads();
  #pragma unroll
  for (int it = 0; it < 4; ++it){
    int idx = it*256 + threadIdx.x;
    int ro = idx >> 4, co4 = (idx & 15) * 4;
    us4 v; v.x=t[ro][co4]; v.y=t[ro][co4+1]; v.z=t[ro][co4+2]; v.w=t[ro][co4+3];
    *(us4*)(o + (long long)(cb+ro)*LDA + rb + co4) = v;
  }
}

// ======= fused t0: BM=256, BN=128, 8 waves (4M x 2N, wave 64x64) =======
// Reads f32 g (reg-staged, converts), writes g16 in TILED staging order +
// bf16 t0 partials. B (zT) via gl_lds. LDS (32+16)KB x2 = 96 KB.
__global__ __launch_bounds__(512)
void k_gemm_t0(const float* __restrict__ g, const unsigned short* __restrict__ zT,
               unsigned short* __restrict__ g16, unsigned short* __restrict__ P, int S)
{
  constexpr int ldp = 128;
  __shared__ unsigned short sm[2][24576];   // A 16384 + B 8192 shorts

  const int tid = threadIdx.x;
  const int wid = tid >> 6, l = tid & 63;
  const int wm = wid >> 1, wn = wid & 1;
  const int lr = l & 15, lk = l >> 4;
  const int mtile = blockIdx.x;
  const int mBase = mtile * 256;
  const int s = blockIdx.z;
  const int kt0 = (157*s)/S, kt1 = (157*(s+1))/S;

  int arow[4], acol8[4];
  #pragma unroll
  for (int i = 0; i < 4; ++i){
    int ch = tid + 512*i;
    int row = ch >> 3, gr = ch & 7;
    arow[i] = row; acol8[i] = ((gr ^ (row & 7)) * 8);
  }
  float fA[4][8];
  auto loadA = [&](int kt){
    #pragma unroll
    for (int i = 0; i < 4; ++i){
      int grow = mBase + arow[i];
      int col = kt*64 + acol8[i];
      if (grow < 10000 && col < 10000){
        float4 x = *(const float4*)(g + (long long)grow*10000 + col);
        float4 y = *(const float4*)(g + (long long)grow*10000 + col + 4);
        fA[i][0]=x.x; fA[i][1]=x.y; fA[i][2]=x.z; fA[i][3]=x.w;
        fA[i][4]=y.x; fA[i][5]=y.y; fA[i][6]=y.z; fA[i][7]=y.w;
      } else {
        #pragma unroll
        for (int j = 0; j < 8; ++j) fA[i][j] = 0.f;
      }
    }
  };
  auto writeA = [&](int buf, int kt){
    unsigned short* gt = g16 + ((long long)mtile*157 + kt)*GTILE;
    #pragma unroll
    for (int i = 0; i < 4; ++i){
      int ch = tid + 512*i;
      short8 v = pack8(fA[i]);
      *(short8*)(&sm[buf][ch*8]) = v;
      *(short8*)(gt + ch*8) = v;               // tiled staging-order write
    }
  };
  auto stageB = [&](int buf, int kt){
    unsigned short* dst = &sm[buf][16384];
    const unsigned short* Bk = zT + (long long)kt*64;
    #pragma unroll
    for (int i = 0; i < 2; ++i){
      int c = i*512 + tid; int row = c >> 3, gr = c & 7;
      gl_lds16(Bk + (long long)row*LDA + ((gr ^ (row & 7))*8), dst + c*8);
    }
  };

  f32x4 acc[4][4];
  #pragma unroll
  for (int i = 0; i < 4; ++i)
    #pragma unroll
    for (int j = 0; j < 4; ++j){ f32x4 zz = {0.f,0.f,0.f,0.f}; acc[i][j] = zz; }

  loadA(kt0); stageB(0, kt0); writeA(0, kt0);
  int cur = 0;
  for (int kt = kt0; kt < kt1; ++kt){
    __syncthreads();
    const bool pf = (kt + 1 < kt1);
    if (pf){ loadA(kt+1); stageB(cur^1, kt+1); }
    const unsigned short* sp = &sm[cur][0];
    #pragma unroll
    for (int ks = 0; ks < 2; ++ks){
      short8 a[4];
      #pragma unroll
      for (int i = 0; i < 4; ++i){
        int row = wm*64 + i*16 + lr;
        a[i] = *(const short8*)(sp + row*64 + (((4*ks+lk) ^ (row & 7))*8));
      }
      #pragma unroll
      for (int j = 0; j < 4; ++j){
        int rb = wn*64 + j*16 + lr;
        short8 b = *(const short8*)(sp + 16384 + rb*64 + (((4*ks+lk) ^ (rb & 7))*8));
        #pragma unroll
        for (int i = 0; i < 4; ++i)
          acc[i][j] = MFMA16(a[i], b, acc[i][j]);
      }
    }
    if (pf) writeA(cur^1, kt+1);
    cur ^= 1;
  }

  unsigned short* Pp = P + (long long)s*MROWS*ldp;
  #pragma unroll
  for (int i = 0; i < 4; ++i){
    const int row0 = mBase + wm*64 + i*16 + lk*4;
    #pragma unroll
    for (int j = 0; j < 4; ++j){
      const int col = wn*64 + j*16 + lr;
      #pragma unroll
      for (int r = 0; r < 4; ++r)
        Pp[(long long)(row0+r)*ldp + col] = f2bf(acc[i][j][r]);
    }
  }
}

// ======= 256xBN GEMM, split-K, bf16 partials; A from TILED g16 =======
template<int BN>
__global__ __launch_bounds__(512)
void k_gemm8(const unsigned short* __restrict__ A,
             const unsigned short* __restrict__ B,
             unsigned short* __restrict__ P, int S, int ldp, int nBase)
{
  constexpr int WNS = BN/4;
  constexpr int NJ  = WNS/16;
  constexpr int BCH = BN/64;
  __shared__ unsigned short sm[2][16384 + BN*64];

  const int tid = threadIdx.x;
  const int wid = tid >> 6, l = tid & 63;
  const int wm = wid >> 2, wn = wid & 3;
  const int lr = l & 15, lk = l >> 4;
  const int mBase = blockIdx.x * 256;
  const int s = blockIdx.z;
  const int kt0 = (157*s)/S, kt1 = (157*(s+1))/S;

  // A: linear tiled stream (contiguous 32 KB per K-tile per block)
  const unsigned short* Abase = A + (long long)blockIdx.x*157*GTILE + tid*8;
  // B: row-major transposed operand, swizzled source (unchanged)
  const unsigned short* gsrcB[BCH];
  int ldstB[BCH];
  #pragma unroll
  for (int i = 0; i < BCH; ++i){
    int ch = tid + 512*i;
    int row = ch >> 3, gc = (ch & 7) ^ (row & 7);
    gsrcB[i] = B + (long long)(nBase + row)*LDA + gc*8;
    ldstB[i] = 16384 + ch*8;
  }
  auto stage_tile = [&](unsigned short* dst, int kt){
    const unsigned short* Ak = Abase + (long long)kt*GTILE;
    #pragma unroll
    for (int i = 0; i < 4; ++i)
      gl_lds16(Ak + i*4096, dst + tid*8 + i*4096);
    const long long ko = (long long)kt * 64;
    #pragma unroll
    for (int i = 0; i < BCH; ++i)
      gl_lds16(gsrcB[i] + ko, dst + ldstB[i]);
  };

  f32x4 acc[8][NJ];
  #pragma unroll
  for (int i = 0; i < 8; ++i)
    #pragma unroll
    for (int j = 0; j < NJ; ++j){ f32x4 zz = {0.f,0.f,0.f,0.f}; acc[i][j] = zz; }

  stage_tile(&sm[0][0], kt0);

  int cur = 0;
  for (int kt = kt0; kt < kt1; ++kt){
    const bool pf = (kt + 1 < kt1);
    unsigned short* nb = &sm[cur ^ 1][0];
    const unsigned short* sp = &sm[cur][0];

    if (pf){
      stage_tile(nb, kt + 1);
      __builtin_amdgcn_sched_barrier(0);
      if constexpr (BN == 256) asm volatile("s_waitcnt vmcnt(8)" ::: "memory");
      else                     asm volatile("s_waitcnt vmcnt(6)" ::: "memory");
    } else {
      asm volatile("s_waitcnt vmcnt(0)" ::: "memory");
    }
    __builtin_amdgcn_sched_barrier(0);
    __builtin_amdgcn_s_barrier();
    __builtin_amdgcn_sched_barrier(0);

    short8 bfr[NJ][2];
    #pragma unroll
    for (int jj = 0; jj < NJ; ++jj){
      const int row = wn*WNS + jj*16 + lr;
      #pragma unroll
      for (int ks = 0; ks < 2; ++ks)
        bfr[jj][ks] = *(const short8*)(sp + 16384 + row*64 + (((ks*4+lk) ^ (row & 7))*8));
    }
    #pragma unroll
    for (int ih = 0; ih < 2; ++ih){
      short8 af[4][2];
      #pragma unroll
      for (int ii = 0; ii < 4; ++ii){
        const int row = wm*128 + ih*64 + ii*16 + lr;
        #pragma unroll
        for (int ks = 0; ks < 2; ++ks)
          af[ii][ks] = *(const short8*)(sp + row*64 + (((ks*4+lk) ^ (row & 7))*8));
      }
      __builtin_amdgcn_s_setprio(1);
      #pragma unroll
      for (int ks = 0; ks < 2; ++ks)
        #pragma unroll
        for (int ii = 0; ii < 4; ++ii)
          #pragma unroll
          for (int jj = 0; jj < NJ; ++jj)
            acc[ih*4+ii][jj] = MFMA16(af[ii][ks], bfr[jj][ks], acc[ih*4+ii][jj]);
      __builtin_amdgcn_s_setprio(0);
    }
    __builtin_amdgcn_sched_barrier(0);
    __builtin_amdgcn_s_barrier();
    __builtin_amdgcn_sched_barrier(0);
    cur ^= 1;
  }

  unsigned short* Pp = P + (long long)s*MROWS*ldp;
  #pragma unroll
  for (int i = 0; i < 8; ++i){
    const int row0 = mBase + wm*128 + i*16 + lk*4;
    #pragma unroll
    for (int j = 0; j < NJ; ++j){
      const int col = nBase + wn*WNS + j*16 + lr;
      #pragma unroll
      for (int r = 0; r < 4; ++r)
        Pp[(long long)(row0+r)*ldp + col] = f2bf(acc[i][j][r]);
    }
  }
}

// ---- fused small GEMM over summed bf16 partials ----
// MODE 0: (optional relu) -> o1 = outT bf16 [NW][10048]
// MODE 1: relu -> o3 = z_ row [10000][256]; rownorm -> o1 = znT, o2 = zn row
template<int NW, int KW, int LDP, int S, int MODE>
__global__ __launch_bounds__(320)
void k_small(const unsigned short* __restrict__ P,
             const unsigned short* __restrict__ W,
             unsigned short* __restrict__ o1,
             unsigned short* __restrict__ o2,
             unsigned short* __restrict__ o3,
             int doRelu)
{
  const int tid = threadIdx.x, w = tid >> 6, l = tid & 63;
  const int lr = l & 15, lk = l >> 4;
  const int mBase = blockIdx.x * 80;
  constexpr int NF = NW/16;
  constexpr long long SSTR = MROWS*(long long)LDP;

  f32x4 acc[NF];
  #pragma unroll
  for (int f = 0; f < NF; ++f){ f32x4 zz = {0.f,0.f,0.f,0.f}; acc[f] = zz; }

  const unsigned short* ap = P + (long long)(mBase + 16*w + lr)*LDP + lk*8;
  #pragma unroll
  for (int kc = 0; kc < KW/32; ++kc){
    float av[8];
    short8 v0 = *(const short8*)(ap + kc*32);
    #pragma unroll
    for (int e = 0; e < 8; ++e) av[e] = bf2f((unsigned short)v0[e]);
    #pragma unroll
    for (int s2 = 1; s2 < S; ++s2){
      short8 v = *(const short8*)(ap + (long long)s2*SSTR + kc*32);
      #pragma unroll
      for (int e = 0; e < 8; ++e) av[e] += bf2f((unsigned short)v[e]);
    }
    short8 a = pack8(av);
    #pragma unroll
    for (int f = 0; f < NF; ++f){
      short8 b = *(const short8*)(W + (long long)(16*f+lr)*KW + kc*32 + lk*8);
      acc[f] = MFMA16(a, b, acc[f]);
    }
  }

  const int row0 = mBase + 16*w + lk*4;
  if constexpr (MODE == 0){
    #pragma unroll
    for (int f = 0; f < NF; ++f){
      us4 v;
      #pragma unroll
      for (int r = 0; r < 4; ++r){
        float x = acc[f][r];
        if (doRelu) x = fmaxf(x, 0.0f);
        v[r] = f2bf(x);
      }
      *(us4*)(o1 + (long long)(16*f+lr)*LDA + row0) = v;
    }
  } else {
    float ss[4] = {0.f,0.f,0.f,0.f};
    #pragma unroll
    for (int f = 0; f < NF; ++f)
      #pragma unroll
      for (int r = 0; r < 4; ++r){
        float v = fmaxf(acc[f][r], 0.0f);
        acc[f][r] = v;
        ss[r] += v*v;
      }
    #pragma unroll
    for (int r = 0; r < 4; ++r){
      #pragma unroll
      for (int off = 1; off <= 8; off <<= 1)
        ss[r] += __shfl_xor(ss[r], off, 64);
      ss[r] = 1.0f / fmaxf(sqrtf(ss[r]), 1e-12f);
    }
    #pragma unroll
    for (int f = 0; f < NF; ++f){
      const int col = 16*f + lr;
      us4 vn;
      #pragma unroll
      for (int r = 0; r < 4; ++r){
        float zr = acc[f][r];
        float nr = zr * ss[r];
        vn[r] = f2bf(nr);
        o2[(long long)(row0+r)*256 + col] = vn[r];     // zn row-major
        o3[(long long)(row0+r)*256 + col] = f2bf(zr);  // z_ row-major
      }
      *(us4*)(o1 + (long long)col*LDA + row0) = vn;    // znT
    }
  }
}

// ---- fused reduce(bf16 partials) + APPNP epilogue + TRANSPOSED write ----
__global__ void k_reduce_T(const unsigned short* __restrict__ P, int S, int ldp, int colOff,
                           unsigned short* __restrict__ outT,
                           const unsigned short* __restrict__ H)
{
  __shared__ unsigned short t[64][65];
  const int rb = blockIdx.x*64, cb = blockIdx.y*64;
  const long long stride = MROWS * (long long)ldp;
  #pragma unroll
  for (int it = 0; it < 4; ++it){
    int idx = it*256 + threadIdx.x;
    int r = idx >> 4, c4 = (idx & 15)*4;
    int row = rb + r;
    float sv[4] = {0.f,0.f,0.f,0.f};
    if (row < 10000){
      const unsigned short* p = P + (long long)row*ldp + colOff + cb + c4;
      for (int s2 = 0; s2 < S; ++s2){
        us4 tt = *(const us4*)(p + (long long)s2*stride);
        sv[0] += bf2f(tt.x); sv[1] += bf2f(tt.y);
        sv[2] += bf2f(tt.z); sv[3] += bf2f(tt.w);
      }
      us4 h = *(const us4*)(H + (long long)row*256 + cb + c4);
      sv[0] = 0.5f*sv[0] + 0.5f*bf2f(h.x);
      sv[1] = 0.5f*sv[1] + 0.5f*bf2f(h.y);
      sv[2] = 0.5f*sv[2] + 0.5f*bf2f(h.z);
      sv[3] = 0.5f*sv[3] + 0.5f*bf2f(h.w);
    }
    t[c4+0][r] = f2bf(sv[0]); t[c4+1][r] = f2bf(sv[1]);
    t[c4+2][r] = f2bf(sv[2]); t[c4+3][r] = f2bf(sv[3]);
  }
  __syncthreads();
  #pragma unroll
  for (int it = 0; it < 4; ++it){
    int idx = it*256 + threadIdx.x;
    int ro = idx >> 4, co4 = (idx & 15)*4;
    us4 v; v.x=t[ro][co4]; v.y=t[ro][co4+1]; v.z=t[ro][co4+2]; v.w=t[ro][co4+3];
    *(us4*)(outT + (long long)(cb+ro)*LDA + rb + co4) = v;
  }
}

// ---- reduce partials + sigmoid -> f32 res [10000][128] ----
__global__ void k_reduce_sig(const unsigned short* __restrict__ P, int S,
                             float* __restrict__ out)
{
  const long long stride = MROWS * 128LL;
  const int idx = blockIdx.x*256 + threadIdx.x;
  const int row = idx >> 5;
  const int c4 = (idx & 31)*4;
  const unsigned short* p = P + (long long)row*128 + c4;
  float sv[4] = {0.f,0.f,0.f,0.f};
  for (int s2 = 0; s2 < S; ++s2){
    us4 tt = *(const us4*)(p + (long long)s2*stride);
    sv[0] += bf2f(tt.x); sv[1] += bf2f(tt.y);
    sv[2] += bf2f(tt.z); sv[3] += bf2f(tt.w);
  }
  float4 o;
  o.x = 1.0f/(1.0f + expf(-sv[0]));
  o.y = 1.0f/(1.0f + expf(-sv[1]));
  o.z = 1.0f/(1.0f + expf(-sv[2]));
  o.w = 1.0f/(1.0f + expf(-sv[3]));
  *(float4*)(out + (long long)row*128 + c4) = o;
}

// ---- final reduce: Z3 = 0.5*sum + 0.5*zn -> f32 out ----
__global__ void k_reduce2(const unsigned short* __restrict__ P, int S, int ldp,
                          float* __restrict__ out, const unsigned short* __restrict__ H)
{
  const long long stride = MROWS * (long long)ldp;
  const int idx = blockIdx.x*256 + threadIdx.x;
  const int row = idx >> 6;
  const int c4 = (idx & 63)*4;
  const unsigned short* p = P + (long long)row*ldp + c4;
  float sv[4] = {0.f,0.f,0.f,0.f};
  for (int s2 = 0; s2 < S; ++s2){
    us4 tt = *(const us4*)(p + (long long)s2*stride);
    sv[0] += bf2f(tt.x); sv[1] += bf2f(tt.y);
    sv[2] += bf2f(tt.z); sv[3] += bf2f(tt.w);
  }
  us4 h = *(const us4*)(H + (long long)row*256 + c4);
  float4 o;
  o.x = 0.5f*sv[0] + 0.5f*bf2f(h.x);
  o.y = 0.5f*sv[1] + 0.5f*bf2f(h.y);
  o.z = 0.5f*sv[2] + 0.5f*bf2f(h.z);
  o.w = 0.5f*sv[3] + 0.5f*bf2f(h.w);
  *(float4*)(out + (long long)row*256 + c4) = o;
}

extern "C" void kernel_launch(void* const* d_in, const int* in_sizes, int n_in,
                              void* d_out, int out_size, void* d_ws, size_t ws_size,
                              hipStream_t stream)
{
  const float* g   = (const float*)d_in[0];
  const float* z   = (const float*)d_in[1];
  const float* W1  = (const float*)d_in[2];
  const float* W1_ = (const float*)d_in[3];
  const float* W2  = (const float*)d_in[4];

  char* ws = (char*)d_ws;
  size_t off = 0;
  auto alloc = [&](size_t bytes)->void*{
    void* p = ws + off; off += (bytes + 255) & ~(size_t)255; return p;
  };
  unsigned short* g16  = (unsigned short*)alloc(40ULL*157*GTILE*2);  // tiled, 206 MB
  unsigned short* zT   = (unsigned short*)alloc(128ULL*10048*2);
  unsigned short* W1c  = (unsigned short*)alloc(256ULL*128*2);
  unsigned short* W1_c = (unsigned short*)alloc(256ULL*256*2);
  unsigned short* W2c  = (unsigned short*)alloc(128ULL*256*2);
  unsigned short* Tbuf = (unsigned short*)alloc(512ULL*10048*2);
  unsigned short* zn   = (unsigned short*)alloc(10000ULL*256*2);
  unsigned short* Xbuf = (unsigned short*)alloc(10000ULL*256*2);
  unsigned short* P    = (unsigned short*)alloc(10240ULL*1536*2);
  (void)ws_size; (void)in_sizes; (void)n_in; (void)out_size;

  float* res  = (float*)d_out;
  float* Zout = (float*)d_out + 10000LL*128;
  unsigned short* y2T = Tbuf + 256LL*LDA;

  k_zero<<<dim3(12), dim3(256), 0, stream>>>(Tbuf);
  k_tconv_z<<<dim3(157,2), dim3(256), 0, stream>>>(z, zT);
  k_conv_w<<<dim3(120), dim3(256), 0, stream>>>(W1, W1c, 256*128/4,
                                                W1_, W1_c, 256*256/4,
                                                W2, W2c, 128*256/4);

  // t0 = g @ z (writes tiled g16 + partials), S=6
  k_gemm_t0<<<dim3(40,1,6), dim3(512), 0, stream>>>(g, zT, g16, P, 6);
  // z1^T -> Tbuf rows 0..255
  k_small<256,128,128,6,0><<<dim3(125), dim3(320), 0, stream>>>(P, W1c, Tbuf, nullptr, nullptr, 1);
  // t1 = g @ z1
  k_gemm8<256><<<dim3(40,1,6), dim3(512), 0, stream>>>(g16, Tbuf, P, 6, 256, 0);
  // znT -> Tbuf, zn row, z_ row -> Xbuf
  k_small<256,256,256,6,1><<<dim3(125), dim3(320), 0, stream>>>(P, W1_c, Tbuf, zn, Xbuf, 0);
  // y2^T = T(z_ @ W2^T) -> Tbuf rows 256..383
  k_small<128,256,256,1,0><<<dim3(125), dim3(320), 0, stream>>>(Xbuf, W2c, y2T, nullptr, nullptr, 0);
  // u1 = g @ zn
  k_gemm8<256><<<dim3(40,1,6), dim3(512), 0, stream>>>(g16, Tbuf, P, 6, 256, 0);
  // Z1^T -> Tbuf rows 0..255
  k_reduce_T<<<dim3(157,4), dim3(256), 0, stream>>>(P, 6, 256, 0, Tbuf, zn);
  // r = g @ y2 (N=128)
  k_gemm8<128><<<dim3(40,1,6), dim3(512), 0, stream>>>(g16, y2T, P, 6, 128, 0);
  // res = sigmoid(r)
  k_reduce_sig<<<dim3(1250), dim3(256), 0, stream>>>(P, 6, res);
  // Z2
  k_gemm8<256><<<dim3(40,1,6), dim3(512), 0, stream>>>(g16, Tbuf, P, 6, 256, 0);
  k_reduce_T<<<dim3(157,4), dim3(256), 0, stream>>>(P, 6, 256, 0, Tbuf, zn);
  // Z3 -> f32 d_out
  k_gemm8<256><<<dim3(40,1,6), dim3(512), 0, stream>>>(g16, Tbuf, P, 6, 256, 0);
  k_reduce2<<<dim3(2500), dim3(256), 0, stream>>>(P, 6, 256, Zout, zn);
}